// Round 10
// baseline (1968.949 us; speedup 1.0000x reference)
//
#include <hip/hip_runtime.h>
#include <hip/hip_bf16.h>
#include <cstdint>
#include <cstddef>

// MMDecoderDoubleBranch R16 = R14 (best 1702us) + software-pipelined epilogues.
// R15 (drain-free ring) was FLAT -> neither vmcnt drain nor load latency is
// the gating cost; reverted to R14 skeleton. Pipe accounting: MFMA 13% (=242us
// ~ dense floor), LDS ~35%, real VALU ~25% -> ~60% all-stall = serial epilogue
// chains inside barrier regions (LSTM gate epis ~200cyc x8, mode GN2+outproj
// ~500cyc x6, all DEPENDENT on their own region's gemm -> no overlap at ~1.75
// waves/SIMD). Fix (proven pattern of R13/R14: remove serialized work between
// barriers):
//  (a) LSTM: epilogue(cg-1) runs in cg's region (gp/gc state; independent of
//      current MFMAs -> scheduler interleaves VALU under MFMA/lgkm waits).
//  (b) modes: GN2+outproj of mode m-1 deferred into mode m's gemm1 region
//      (acc2->a2p; final epi after loop, before relw-reading step tail).
//  (c) s_setprio(1) around MFMA clusters (2 drifting blocks/CU = role
//      diversity; T5).
// Cost: ~+50 VGPR (->~180, still 2 waves/SIMD), ~5us reg copies.
// Everything else byte-identical to R14 (32 chunks/step, 2x20KB stage,
// DPP GN, packed params, batched stores, rolled loops, 81920B LDS).

#define HD 128
#define TT 30
#define MM 6
#define B_ROWS 32768

typedef _Float16 f16x8 __attribute__((ext_vector_type(8)));
typedef _Float16 f16x4 __attribute__((ext_vector_type(4)));
typedef float f32x4 __attribute__((ext_vector_type(4)));

__device__ __forceinline__ float fast_rcp(float x) { return __builtin_amdgcn_rcpf(x); }
__device__ __forceinline__ float sigm(float x) { return fast_rcp(1.f + __expf(-x)); }
__device__ __forceinline__ float tanhf_(float x) { return 1.f - 2.f * fast_rcp(__expf(2.f * x) + 1.f); }
__device__ __forceinline__ float selu_(float x) {
  const float sc = 1.0507009873554805f;
  const float al = 1.6732632423543772f;
  return x > 0.f ? sc * x : sc * al * (__expf(x) - 1.f);
}

// ---- DPP row (16-lane) sum: every lane gets the sum of its 16-lane group ----
template <int CTRL>
__device__ __forceinline__ float dpp_add(float x) {
  union { float f; int i; } a, b;
  a.f = x;
  b.i = __builtin_amdgcn_update_dpp(a.i, a.i, CTRL, 0xF, 0xF, false);
  return x + b.f;
}
__device__ __forceinline__ float rowsum16(float x) {
  x = dpp_add<0x128>(x);  // row_ror:8
  x = dpp_add<0x124>(x);  // row_ror:4
  x = dpp_add<0x122>(x);  // row_ror:2
  x = dpp_add<0x121>(x);  // row_ror:1
  return x;
}
__device__ __forceinline__ f32x4 rowsum16x4(f32x4 v) {
  v[0] = rowsum16(v[0]); v[1] = rowsum16(v[1]);
  v[2] = rowsum16(v[2]); v[3] = rowsum16(v[3]);
  return v;
}

// ---- weight prep: fragment-ordered f16 + packed epilogue params (== R14) ----
__global__ __launch_bounds__(256) void prep_weights(
    const float* __restrict__ W_ih, const float* __restrict__ W_hh,
    const float* __restrict__ b_ih, const float* __restrict__ b_hh,
    const float* __restrict__ mW1, const float* __restrict__ mW2,
    const float* __restrict__ cW1, const float* __restrict__ cW2,
    const float* __restrict__ mg1w, const float* __restrict__ mg1b,
    const float* __restrict__ mg2w, const float* __restrict__ mg2b,
    const float* __restrict__ mWo, const float* __restrict__ W_se,
    const float* __restrict__ b_se,
    _Float16* __restrict__ Wg, _Float16* __restrict__ W1p, _Float16* __restrict__ W2p,
    _Float16* __restrict__ cW1p, _Float16* __restrict__ cW2p, float* __restrict__ bg,
    float* __restrict__ ppA, float* __restrict__ ppB, float* __restrict__ ppC) {
  int n = blockIdx.x * 256 + threadIdx.x;
  if (n < 81920) {
    int t16 = n / 2560, r = n % 2560;
    int ch = r / 512, l = (r >> 3) & 63, j = r & 7;
    int q = l >> 4, cl = l & 15;
    int cg = t16 >> 2, g = t16 & 3;            // cg-major tile order
    int row = g * 128 + cg * 16 + cl;          // gate-major output row
    int k = ch * 32 + q * 8 + j;
    float v = 0.f;
    if (k < 128) v = W_hh[row * 128 + k];
    else if (k < 144) v = W_ih[row * 16 + (k - 128)];
    Wg[n] = (_Float16)v;
    return;
  }
  n -= 81920;
  if (n < 98304) {
    int m = n >> 14, r = n & 16383;
    int ct = r >> 11, ch = (r >> 9) & 3, l = (r >> 3) & 63, j = r & 7;
    int q = l >> 4, cl = l & 15;
    int outcol = ct * 16 + cl, k = ch * 32 + q * 8 + j;
    W1p[n] = (_Float16)mW1[(m * 128 + k) * 128 + outcol];
    return;
  }
  n -= 98304;
  if (n < 98304) {
    int m = n >> 14, r = n & 16383;
    int ct = r >> 11, ch = (r >> 9) & 3, l = (r >> 3) & 63, j = r & 7;
    int q = l >> 4, cl = l & 15;
    int outcol = ct * 16 + cl, k = ch * 32 + q * 8 + j;
    W2p[n] = (_Float16)mW2[(m * 128 + k) * 128 + outcol];
    return;
  }
  n -= 98304;
  if (n < 16384) {
    int ct = n >> 11, ch = (n >> 9) & 3, l = (n >> 3) & 63, j = n & 7;
    int q = l >> 4, cl = l & 15;
    int outcol = ct * 16 + cl, k = ch * 32 + q * 8 + j;
    cW1p[n] = (_Float16)cW1[k * 128 + outcol];
    return;
  }
  n -= 16384;
  if (n < 16384) {
    int ct = n >> 11, ch = (n >> 9) & 3, l = (n >> 3) & 63, j = n & 7;
    int q = l >> 4, cl = l & 15;
    int outcol = ct * 16 + cl, k = ch * 32 + q * 8 + j;
    cW2p[n] = (_Float16)cW2[k * 128 + outcol];
    return;
  }
  n -= 16384;
  if (n < 512) { bg[n] = b_ih[n] + b_hh[n]; return; }
  n -= 512;
  if (n < 1536) {  // ppA
    int m = n >> 8, r = n & 255;
    int cl = r >> 4, k = r & 15;
    float v = (k < 8) ? mg1w[m * 128 + k * 16 + cl] : mg1b[m * 128 + (k - 8) * 16 + cl];
    ppA[n] = v;
    return;
  }
  n -= 1536;
  if (n < 3072) {  // ppB
    int m = n >> 9, r = n & 511;
    int cl = r >> 5, k = r & 31;
    int ct = k & 7, sel = k >> 3;
    float v;
    if (sel == 0)      v = mg2w[m * 128 + ct * 16 + cl];
    else if (sel == 1) v = mg2b[m * 128 + ct * 16 + cl];
    else               v = mWo[((size_t)m * 128 + ct * 16 + cl) * 2 + (sel - 2)];
    ppB[n] = v;
    return;
  }
  n -= 3072;
  if (n < 224) {  // ppC
    int g = n / 56, k = n % 56;
    float v = 0.f;
    if (k < 48)      v = W_se[(g * 4 + k / 12) * 12 + (k % 12)];
    else if (k < 52) v = b_se[g * 4 + (k - 48)];
    ppC[n] = v;
    return;
  }
}

// chunk schedule (32 chunks/step, same weights every step):
//   idx 0..7  : Wg + idx*10240, 20 x 1KB
//   idx 8..31 : j=idx-8, m=j>>2, r=j&3 -> (r<2?W1p:W2p)+m*16384+(r&1)*8192, 16 x 1KB
__device__ __forceinline__ void stage_chunk(int idx, _Float16* dst, int w, int lane,
                                            const _Float16* __restrict__ Wg,
                                            const _Float16* __restrict__ W1p,
                                            const _Float16* __restrict__ W2p) {
  const _Float16* src;
  int nblk;
  if (idx < 8) {
    src = Wg + idx * 10240;
    nblk = 20;
  } else {
    int j = idx - 8, m = j >> 2, r = j & 3;
    src = ((r & 2) ? W2p : W1p) + m * 16384 + (r & 1) * 8192;
    nblk = 16;
  }
  for (int i = w; i < nblk; i += 4) {
    __builtin_amdgcn_global_load_lds(
        (const __attribute__((address_space(1))) void*)(src + i * 512 + lane * 8),
        (__attribute__((address_space(3))) void*)(dst + i * 512 + lane * 8),
        16, 0, 0);
  }
}

__device__ __forceinline__ f32x4 mfma16(f16x8 a, f16x8 b, f32x4 c) {
  return __builtin_amdgcn_mfma_f32_16x16x32_f16(a, b, c, 0, 0, 0);
}

// one half (4 col-tiles) of a 16x128 GEMM slice from a staged LDS buffer
__device__ __forceinline__ void gemm_half(const f16x8 (&a)[4], const _Float16* buf,
                                          int lane, f32x4 (&acc)[8], int base) {
  __builtin_amdgcn_s_setprio(1);
#pragma unroll
  for (int ctl = 0; ctl < 4; ++ctl) {
    const _Float16* bp = buf + ctl * 2048 + lane * 8;
    f32x4 a0 = {0.f, 0.f, 0.f, 0.f};
#pragma unroll
    for (int ch = 0; ch < 4; ++ch) {
      f16x8 b = *(const f16x8*)(bp + ch * 512);
      a0 = mfma16(a[ch], b, a0);
    }
    acc[base + ctl] = a0;
  }
  __builtin_amdgcn_s_setprio(0);
}

// ---- main decoder: 512 blocks x 4 waves; wave owns 16 rows end-to-end ----
__global__ __launch_bounds__(256, 2) void mmdec_main(
    const float* __restrict__ last_obs_rel, const float* __restrict__ h0, const float* __restrict__ c0,
    const float* __restrict__ mbo, const float* __restrict__ cg1w, const float* __restrict__ cg1b,
    const float* __restrict__ cg2w, const float* __restrict__ cg2b,
    const float* __restrict__ cWo, const float* __restrict__ cbo,
    const _Float16* __restrict__ Wg, const _Float16* __restrict__ W1p, const _Float16* __restrict__ W2p,
    const _Float16* __restrict__ cW1p, const _Float16* __restrict__ cW2p, const float* __restrict__ bgp,
    const float* __restrict__ ppA, const float* __restrict__ ppB, const float* __restrict__ ppC,
    float* __restrict__ out) {
  // LDS map (bytes): stage 2x20480 | h 64x320 | t1 64x272 | rel 64x12 f32
  __shared__ __align__(16) unsigned char smem[81920];
  _Float16* stage0 = (_Float16*)smem;                       // [0, 40960)
  unsigned char* h_base = smem + 40960;                     // [40960, 61440)
  unsigned char* t1_base = smem + 61440;                    // [61440, 78848)
  float* rel_all = (float*)(smem + 78848);                  // [78848, 81920)

  const int tid = threadIdx.x;
  const int w = tid >> 6;       // wave id 0..3: owns rows [16w, 16w+16) of block
  const int lane = tid & 63;
  const int q = lane >> 4, cl = lane & 15;
  const int rowbase = blockIdx.x * 64 + w * 16;             // wave's first global row

  auto hrow = [&](int r) -> _Float16* { return (_Float16*)(h_base + (w * 16 + r) * 320); };
  auto t1row = [&](int r) -> _Float16* { return (_Float16*)(t1_base + (w * 16 + r) * 272); };
  float* relw = rel_all + w * 16 * 12;

  auto sbuf = [&](int idx) -> _Float16* { return stage0 + ((idx & 1) ? 10240 : 0); };

  // ---- init: h0 -> LDS f16 (quarter row per lane, float4 loads) ----
  {
    const int rr = lane & 15, seg = lane >> 4;
    const float* src = h0 + (size_t)(rowbase + rr) * HD + seg * 32;
    _Float16* dst = hrow(rr) + seg * 32;
#pragma unroll
    for (int i = 0; i < 32; i += 8) {
      f32x4 a = *(const f32x4*)(src + i);
      f32x4 b = *(const f32x4*)(src + i + 4);
      f16x8 v;
#pragma unroll
      for (int k = 0; k < 4; ++k) { v[k] = (_Float16)a[k]; v[4 + k] = (_Float16)b[k]; }
      *(f16x8*)(dst + i) = v;
    }
    // x = selu(tile(last_obs_rel,6) @ W_se.T + b_se); 4 E-cols per lane
    const float r0 = last_obs_rel[(size_t)(rowbase + rr) * 2 + 0];
    const float r1 = last_obs_rel[(size_t)(rowbase + rr) * 2 + 1];
    const int e0 = seg * 4;
    f16x4 v;
#pragma unroll
    for (int i = 0; i < 4; ++i) {
      float acc = ppC[seg * 56 + 48 + i];
#pragma unroll
      for (int j = 0; j < 12; ++j) acc += ((j & 1) ? r1 : r0) * ppC[seg * 56 + i * 12 + j];
      v[i] = (_Float16)selu_(acc);
    }
    *(f16x4*)(hrow(rr) + 128 + e0) = v;
    if (lane < 16) {  // zero pad cols 144..159
      f16x8 z;
#pragma unroll
      for (int i = 0; i < 8; ++i) z[i] = (_Float16)0.f;
      *(f16x8*)(hrow(lane) + 144) = z;
      *(f16x8*)(hrow(lane) + 152) = z;
    }
  }
  // ---- init: c0 in C-layout regs [cg] ----
  f32x4 cacc[8];
#pragma unroll
  for (int cg = 0; cg < 8; ++cg)
#pragma unroll
    for (int r = 0; r < 4; ++r)
      cacc[cg][r] = c0[(size_t)(rowbase + q * 4 + r) * HD + cg * 16 + cl];
  float bgh[8][4];
#pragma unroll
  for (int cg = 0; cg < 8; ++cg)
#pragma unroll
    for (int g = 0; g < 4; ++g) bgh[cg][g] = bgp[g * 128 + cg * 16 + cl];
  f32x4 hc[8];  // h(t) in C-layout (residual source)

  // ---- batched out-store precompute: 96 (row,mode) pairs per wave ----
  const int pA_ = lane, pB_ = 64 + lane;
  const size_t obA = ((size_t)(rowbase + pA_ / 6) * MM + pA_ % 6) * TT;
  const size_t obB = ((size_t)(rowbase + pB_ / 6) * MM + pB_ % 6) * TT;
  const int rlA = (pA_ / 6) * 12 + (pA_ % 6) * 2;
  const int rlB = (pB_ / 6) * 12 + (pB_ % 6) * 2;

  // step-tail W_se pack pointer (per-lane e0 group)
  const float* wsp = ppC + (lane >> 4) * 56;

  // LSTM gate epilogue for cg index cgi, from gate accs gg[4]
  auto lstm_epi = [&](int cgi, const f32x4 (&gg)[4]) {
#pragma unroll
    for (int r = 0; r < 4; ++r) {
      const float iv = sigm(gg[0][r] + bgh[cgi][0]);
      const float fv = sigm(gg[1][r] + bgh[cgi][1]);
      const float gv = tanhf_(gg[2][r] + bgh[cgi][2]);
      const float ov = sigm(gg[3][r] + bgh[cgi][3]);
      const float cn = fv * cacc[cgi][r] + iv * gv;
      cacc[cgi][r] = cn;
      const float hv = ov * tanhf_(cn);
      hc[cgi][r] = hv;
      hrow(q * 4 + r)[cgi * 16 + cl] = (_Float16)hv;
    }
  };

  // deferred GN2+residual+out-proj epilogue for mode mi from saved acc2
  auto gn2_epi = [&](int mi, const f32x4 (&a2)[8]) {
    const float* pBv = ppB + (mi * 16 + cl) * 32;
    const f32x4 g2wA = *(const f32x4*)(pBv);
    const f32x4 g2wB = *(const f32x4*)(pBv + 4);
    const f32x4 g2bA = *(const f32x4*)(pBv + 8);
    const f32x4 g2bB = *(const f32x4*)(pBv + 12);
    const f32x4 w0A  = *(const f32x4*)(pBv + 16);
    const f32x4 w0B  = *(const f32x4*)(pBv + 20);
    const f32x4 w1A  = *(const f32x4*)(pBv + 24);
    const f32x4 w1B  = *(const f32x4*)(pBv + 28);
    f32x4 mean2, rstd2;
    {
      f32x4 s1 = {0.f, 0.f, 0.f, 0.f}, s2 = {0.f, 0.f, 0.f, 0.f};
#pragma unroll
      for (int ct = 0; ct < 8; ++ct) { s1 += a2[ct]; s2 += a2[ct] * a2[ct]; }
      s1 = rowsum16x4(s1); s2 = rowsum16x4(s2);
      mean2 = s1 * (1.f / 128.f);
#pragma unroll
      for (int r = 0; r < 4; ++r)
        rstd2[r] = rsqrtf(s2[r] * (1.f / 128.f) - mean2[r] * mean2[r] + 1e-5f);
    }
    f32x4 po0 = {0.f, 0.f, 0.f, 0.f}, po1 = {0.f, 0.f, 0.f, 0.f};
#pragma unroll
    for (int ct = 0; ct < 8; ++ct) {
      const float g2 = (ct < 4) ? g2wA[ct & 3] : g2wB[ct & 3];
      const float b2 = (ct < 4) ? g2bA[ct & 3] : g2bB[ct & 3];
      const float w0 = (ct < 4) ? w0A[ct & 3] : w0B[ct & 3];
      const float w1 = (ct < 4) ? w1A[ct & 3] : w1B[ct & 3];
#pragma unroll
      for (int r = 0; r < 4; ++r) {
        float v = (a2[ct][r] - mean2[r]) * rstd2[r] * g2 + b2 + hc[ct][r];
        v = fmaxf(v, 0.f);
        po0[r] += v * w0;
        po1[r] += v * w1;
      }
    }
    po0 = rowsum16x4(po0);
    po1 = rowsum16x4(po1);
    if (cl < 2) {
#pragma unroll
      for (int r = 0; r < 4; ++r) {
        const int rl_ = q * 4 + r;
        relw[rl_ * 12 + mi * 2 + cl] = (cl ? po1[r] : po0[r]) + mbo[mi * 2 + cl];
      }
    }
  };

  // prime the pipeline: stage chunk 0
  stage_chunk(0, sbuf(0), w, lane, Wg, W1p, W2p);
  __syncthreads();

  const size_t confbase = (size_t)B_ROWS * MM * TT * 2;

  for (int t = 0; t < TT; ++t) {
    // ======== LSTM: [h|x|0](K=160) @ Wg^T; pipelined gate epilogues ========
    f16x8 afr[5];
#pragma unroll
    for (int ch = 0; ch < 5; ++ch)
      afr[ch] = *(const f16x8*)(hrow(cl) + ch * 32 + q * 8);

    f32x4 gp[4];
    {  // peel cg=0 (no previous epilogue)
      stage_chunk(1, sbuf(1), w, lane, Wg, W1p, W2p);
      const _Float16* buf = sbuf(0);
      __builtin_amdgcn_s_setprio(1);
#pragma unroll
      for (int g = 0; g < 4; ++g) {
        const _Float16* bp = buf + g * 2560 + lane * 8;
        f32x4 a = {0.f, 0.f, 0.f, 0.f};
#pragma unroll
        for (int ch = 0; ch < 5; ++ch) {
          f16x8 b = *(const f16x8*)(bp + ch * 512);
          a = mfma16(afr[ch], b, a);
        }
        gp[g] = a;
      }
      __builtin_amdgcn_s_setprio(0);
      __syncthreads();
    }
    for (int cg = 1; cg < 8; ++cg) {
      stage_chunk((cg + 1) & 31, sbuf(cg + 1), w, lane, Wg, W1p, W2p);
      const _Float16* buf = sbuf(cg);
      f32x4 gc[4];
      __builtin_amdgcn_s_setprio(1);
#pragma unroll
      for (int g = 0; g < 4; ++g) {
        const _Float16* bp = buf + g * 2560 + lane * 8;
        f32x4 a = {0.f, 0.f, 0.f, 0.f};
#pragma unroll
        for (int ch = 0; ch < 5; ++ch) {
          f16x8 b = *(const f16x8*)(bp + ch * 512);
          a = mfma16(afr[ch], b, a);
        }
        gc[g] = a;
      }
      __builtin_amdgcn_s_setprio(0);
      lstm_epi(cg - 1, gp);   // independent of gc -> interleaves with MFMAs
#pragma unroll
      for (int g = 0; g < 4; ++g) gp[g] = gc[g];
      __syncthreads();
    }
    lstm_epi(7, gp);

    // ======== 6 mode heads; GN2 epilogue deferred by one mode ========
    f16x8 frag[4];
#pragma unroll
    for (int ch = 0; ch < 4; ++ch)
      frag[ch] = *(const f16x8*)(hrow(cl) + ch * 32 + q * 8);

    f32x4 a2p[8];  // previous mode's acc2 (deferred epilogue source)
    for (int m = 0; m < MM; ++m) {
      const int base = 8 + m * 4;
      // GN1 params: vector loads issued early; latency hidden under gemm1
      const float* pAv = ppA + (m * 16 + cl) * 16;
      const f32x4 g1wA = *(const f32x4*)(pAv);
      const f32x4 g1wB = *(const f32x4*)(pAv + 4);
      const f32x4 g1bA = *(const f32x4*)(pAv + 8);
      const f32x4 g1bB = *(const f32x4*)(pAv + 12);

      f32x4 acc1[8];
      stage_chunk((base + 1) & 31, sbuf(base + 1), w, lane, Wg, W1p, W2p);
      gemm_half(frag, sbuf(base), lane, acc1, 0);
      if (m > 0) gn2_epi(m - 1, a2p);   // deferred epi overlaps gemm1 half-1
      __syncthreads();
      stage_chunk((base + 2) & 31, sbuf(base + 2), w, lane, Wg, W1p, W2p);
      gemm_half(frag, sbuf(base + 1), lane, acc1, 4);
      // GN1 (DPP rowsum) + relu -> t1; overlaps the staged load
      f32x4 mean, rstd;
      {
        f32x4 s1 = {0.f, 0.f, 0.f, 0.f}, s2 = {0.f, 0.f, 0.f, 0.f};
#pragma unroll
        for (int ct = 0; ct < 8; ++ct) { s1 += acc1[ct]; s2 += acc1[ct] * acc1[ct]; }
        s1 = rowsum16x4(s1); s2 = rowsum16x4(s2);
        mean = s1 * (1.f / 128.f);
#pragma unroll
        for (int r = 0; r < 4; ++r)
          rstd[r] = rsqrtf(s2[r] * (1.f / 128.f) - mean[r] * mean[r] + 1e-5f);
      }
#pragma unroll
      for (int ct = 0; ct < 8; ++ct) {
        const float g1 = (ct < 4) ? g1wA[ct & 3] : g1wB[ct & 3];
        const float b1 = (ct < 4) ? g1bA[ct & 3] : g1bB[ct & 3];
#pragma unroll
        for (int r = 0; r < 4; ++r) {
          float v = (acc1[ct][r] - mean[r]) * rstd[r] * g1 + b1;
          t1row(q * 4 + r)[ct * 16 + cl] = (_Float16)fmaxf(v, 0.f);
        }
      }
      __syncthreads();
      // gemm2 from t1 (same-wave LDS write->read is in-order; no barrier needed)
      f16x8 at1[4];
#pragma unroll
      for (int ch = 0; ch < 4; ++ch)
        at1[ch] = *(const f16x8*)(t1row(cl) + ch * 32 + q * 8);
      f32x4 acc2[8];
      stage_chunk((base + 3) & 31, sbuf(base + 3), w, lane, Wg, W1p, W2p);
      gemm_half(at1, sbuf(base + 2), lane, acc2, 0);
      __syncthreads();
      stage_chunk((base + 4) & 31, sbuf(base + 4), w, lane, Wg, W1p, W2p);
      gemm_half(at1, sbuf(base + 3), lane, acc2, 4);
      // save acc2 for deferred epilogue (epi itself runs next mode / post-loop)
#pragma unroll
      for (int ct = 0; ct < 8; ++ct) a2p[ct] = acc2[ct];
      __syncthreads();
    }
    gn2_epi(5, a2p);   // before step tail reads relw (same-wave in-order)

    // ======== step tail: batched out stores + xin (all wave-local) ========
    {
      float2 vA;
      vA.x = relw[rlA]; vA.y = relw[rlA + 1];
      *(float2*)(out + (obA + t) * 2) = vA;
      if (lane < 32) {
        float2 vB;
        vB.x = relw[rlB]; vB.y = relw[rlB + 1];
        *(float2*)(out + (obB + t) * 2) = vB;
      }
    }
    {
      const int rr = lane & 15;
      const f32x4 rl0 = *(const f32x4*)(relw + rr * 12);
      const f32x4 rl1 = *(const f32x4*)(relw + rr * 12 + 4);
      const f32x4 rl2 = *(const f32x4*)(relw + rr * 12 + 8);
      f32x4 wv0, wv1, wv2, bsv;
      bsv = *(const f32x4*)(wsp + 48);
      f16x4 v;
#pragma unroll
      for (int i = 0; i < 4; ++i) {
        wv0 = *(const f32x4*)(wsp + i * 12);
        wv1 = *(const f32x4*)(wsp + i * 12 + 4);
        wv2 = *(const f32x4*)(wsp + i * 12 + 8);
        float acc = bsv[i];
#pragma unroll
        for (int j = 0; j < 4; ++j) acc += rl0[j] * wv0[j];
#pragma unroll
        for (int j = 0; j < 4; ++j) acc += rl1[j] * wv1[j];
#pragma unroll
        for (int j = 0; j < 4; ++j) acc += rl2[j] * wv2[j];
        v[i] = (_Float16)selu_(acc);
      }
      *(f16x4*)(hrow(rr) + 128 + (lane >> 4) * 4) = v;
    }
    // no barrier: h/x/rel are wave-private; staging WAR is covered by the
    // mode-5 sync above (next overwrite of that buffer is 2 chunks away)
  }

  // ======== confidence head on hT (wave-local; weights from global) ========
  {
    f16x8 frag[4];
#pragma unroll
    for (int ch = 0; ch < 4; ++ch)
      frag[ch] = *(const f16x8*)(hrow(cl) + ch * 32 + q * 8);
    f32x4 acc1[8];
#pragma unroll
    for (int ct = 0; ct < 8; ++ct) {
      const _Float16* bp = cW1p + ct * 2048 + lane * 8;
      f32x4 a0 = {0.f, 0.f, 0.f, 0.f};
#pragma unroll
      for (int ch = 0; ch < 4; ++ch) {
        f16x8 b = *(const f16x8*)(bp + ch * 512);
        a0 = mfma16(frag[ch], b, a0);
      }
      acc1[ct] = a0;
    }
    f32x4 mean, rstd;
    {
      f32x4 s1 = {0.f, 0.f, 0.f, 0.f}, s2 = {0.f, 0.f, 0.f, 0.f};
#pragma unroll
      for (int ct = 0; ct < 8; ++ct) { s1 += acc1[ct]; s2 += acc1[ct] * acc1[ct]; }
      s1 = rowsum16x4(s1); s2 = rowsum16x4(s2);
      mean = s1 * (1.f / 128.f);
#pragma unroll
      for (int r = 0; r < 4; ++r)
        rstd[r] = rsqrtf(s2[r] * (1.f / 128.f) - mean[r] * mean[r] + 1e-5f);
    }
#pragma unroll
    for (int ct = 0; ct < 8; ++ct) {
      const float g1 = cg1w[ct * 16 + cl];
      const float b1 = cg1b[ct * 16 + cl];
#pragma unroll
      for (int r = 0; r < 4; ++r) {
        float v = (acc1[ct][r] - mean[r]) * rstd[r] * g1 + b1;
        t1row(q * 4 + r)[ct * 16 + cl] = (_Float16)fmaxf(v, 0.f);
      }
    }
    f16x8 at1[4];
#pragma unroll
    for (int ch = 0; ch < 4; ++ch)
      at1[ch] = *(const f16x8*)(t1row(cl) + ch * 32 + q * 8);
    f32x4 acc2[8];
#pragma unroll
    for (int ct = 0; ct < 8; ++ct) {
      const _Float16* bp = cW2p + ct * 2048 + lane * 8;
      f32x4 a0 = {0.f, 0.f, 0.f, 0.f};
#pragma unroll
      for (int ch = 0; ch < 4; ++ch) {
        f16x8 b = *(const f16x8*)(bp + ch * 512);
        a0 = mfma16(at1[ch], b, a0);
      }
      acc2[ct] = a0;
    }
    f32x4 mean2, rstd2;
    {
      f32x4 s1 = {0.f, 0.f, 0.f, 0.f}, s2 = {0.f, 0.f, 0.f, 0.f};
#pragma unroll
      for (int ct = 0; ct < 8; ++ct) { s1 += acc2[ct]; s2 += acc2[ct] * acc2[ct]; }
      s1 = rowsum16x4(s1); s2 = rowsum16x4(s2);
      mean2 = s1 * (1.f / 128.f);
#pragma unroll
      for (int r = 0; r < 4; ++r)
        rstd2[r] = rsqrtf(s2[r] * (1.f / 128.f) - mean2[r] * mean2[r] + 1e-5f);
    }
    float pl[4][6];
#pragma unroll
    for (int r = 0; r < 4; ++r)
#pragma unroll
      for (int k = 0; k < 6; ++k) pl[r][k] = 0.f;
#pragma unroll
    for (int ct = 0; ct < 8; ++ct) {
      const float g2 = cg2w[ct * 16 + cl];
      const float b2 = cg2b[ct * 16 + cl];
      float wo[6];
#pragma unroll
      for (int k = 0; k < 6; ++k) wo[k] = cWo[(ct * 16 + cl) * 6 + k];
#pragma unroll
      for (int r = 0; r < 4; ++r) {
        float v = (acc2[ct][r] - mean2[r]) * rstd2[r] * g2 + b2 + hc[ct][r];
        v = fmaxf(v, 0.f);
#pragma unroll
        for (int k = 0; k < 6; ++k) pl[r][k] += v * wo[k];
      }
    }
#pragma unroll
    for (int r = 0; r < 4; ++r)
#pragma unroll
      for (int k = 0; k < 6; ++k) pl[r][k] = rowsum16(pl[r][k]);
    if (cl == 0) {
#pragma unroll
      for (int r = 0; r < 4; ++r) {
        float l[6];
#pragma unroll
        for (int k = 0; k < 6; ++k) l[k] = pl[r][k] + cbo[k];
        float mx = l[0];
#pragma unroll
        for (int k = 1; k < 6; ++k) mx = fmaxf(mx, l[k]);
        float s = 0.f;
#pragma unroll
        for (int k = 0; k < 6; ++k) { l[k] = __expf(l[k] - mx); s += l[k]; }
        const float inv = fast_rcp(s);
#pragma unroll
        for (int k = 0; k < 6; ++k)
          out[confbase + (size_t)(rowbase + q * 4 + r) * 6 + k] = l[k] * inv;
      }
    }
  }
}

extern "C" void kernel_launch(void* const* d_in, const int* in_sizes, int n_in,
                              void* d_out, int out_size, void* d_ws, size_t ws_size,
                              hipStream_t stream) {
  (void)in_sizes; (void)n_in; (void)out_size; (void)ws_size;
  const float* last_obs_rel = (const float*)d_in[1];
  const float* h0   = (const float*)d_in[2];
  const float* c0   = (const float*)d_in[3];
  const float* W_se = (const float*)d_in[4];
  const float* b_se = (const float*)d_in[5];
  const float* W_ih = (const float*)d_in[6];
  const float* W_hh = (const float*)d_in[7];
  const float* b_ih = (const float*)d_in[8];
  const float* b_hh = (const float*)d_in[9];
  const float* mW1  = (const float*)d_in[10];
  const float* mg1w = (const float*)d_in[11];
  const float* mg1b = (const float*)d_in[12];
  const float* mW2  = (const float*)d_in[13];
  const float* mg2w = (const float*)d_in[14];
  const float* mg2b = (const float*)d_in[15];
  const float* mWo  = (const float*)d_in[16];
  const float* mbo  = (const float*)d_in[17];
  const float* cW1  = (const float*)d_in[18];
  const float* cg1w = (const float*)d_in[19];
  const float* cg1b = (const float*)d_in[20];
  const float* cW2  = (const float*)d_in[21];
  const float* cg2w = (const float*)d_in[22];
  const float* cg2b = (const float*)d_in[23];
  const float* cWo  = (const float*)d_in[24];
  const float* cbo  = (const float*)d_in[25];

  char* ws = (char*)d_ws;
  _Float16* Wg   = (_Float16*)(ws + 0);       // 512*160 f16   = 163840 B
  _Float16* W1p  = (_Float16*)(ws + 163840);  // 6*128*128 f16 = 196608 B
  _Float16* W2p  = (_Float16*)(ws + 360448);  // 6*128*128 f16 = 196608 B
  _Float16* cW1p = (_Float16*)(ws + 557056);  // 128*128 f16   =  32768 B
  _Float16* cW2p = (_Float16*)(ws + 589824);  // 128*128 f16   =  32768 B
  float*    bg   = (float*)   (ws + 622592);  // 512 f32       =   2048 B
  float*    ppA  = (float*)   (ws + 624640);  // 1536 f32      =   6144 B
  float*    ppB  = (float*)   (ws + 630784);  // 3072 f32      =  12288 B
  float*    ppC  = (float*)   (ws + 643072);  // 224 f32       =    896 B

  prep_weights<<<1237, 256, 0, stream>>>(W_ih, W_hh, b_ih, b_hh, mW1, mW2, cW1, cW2,
                                         mg1w, mg1b, mg2w, mg2b, mWo, W_se, b_se,
                                         Wg, W1p, W2p, cW1p, cW2p, bg, ppA, ppB, ppC);
  mmdec_main<<<B_ROWS / 64, 256, 0, stream>>>(last_obs_rel, h0, c0,
                                              mbo, cg1w, cg1b, cg2w, cg2b, cWo, cbo,
                                              Wg, W1p, W2p, cW1p, cW2p, bg,
                                              ppA, ppB, ppC, (float*)d_out);
}

// Round 11
// 1921.388 us; speedup vs baseline: 1.0248x; 1.0248x over previous
//
#include <hip/hip_runtime.h>
#include <hip/hip_bf16.h>
#include <cstdint>
#include <cstddef>

// MMDecoderDoubleBranch R17 = R14 (best 1702us) with the t-loop body SHRUNK.
// R16 post-mortem: peeled loops + multi-site epilogue inlining grew the body
// past L1I -> every t-iteration streams code through L2/HBM (FETCH 350MB ->
// 1.16GB, dur +270us). R13->R14 FETCH 166->350MB shows R14 already partially
// streams. Single-variable round: fold gemm1/gemm2 (structurally identical)
// into one rolled gg-loop with shared A[4] fragment regs -- removes one full
// stage+gemm clone per mode (~25-30% of the dominant body), exact R14 barrier
// order preserved. Everything else byte-identical to R14 (32 chunks/step,
// 2x20KB stage double-buffer + syncthreads, DPP rowsum GN, packed params,
// batched stores, rolled loops, 81920B LDS, 2 blocks/CU). No setprio.
// A/B bit: FETCH should drop toward ~250MB; if flat, I$ theory is wrong and
// R14 is the plateau.

#define HD 128
#define TT 30
#define MM 6
#define B_ROWS 32768

typedef _Float16 f16x8 __attribute__((ext_vector_type(8)));
typedef _Float16 f16x4 __attribute__((ext_vector_type(4)));
typedef float f32x4 __attribute__((ext_vector_type(4)));

__device__ __forceinline__ float fast_rcp(float x) { return __builtin_amdgcn_rcpf(x); }
__device__ __forceinline__ float sigm(float x) { return fast_rcp(1.f + __expf(-x)); }
__device__ __forceinline__ float tanhf_(float x) { return 1.f - 2.f * fast_rcp(__expf(2.f * x) + 1.f); }
__device__ __forceinline__ float selu_(float x) {
  const float sc = 1.0507009873554805f;
  const float al = 1.6732632423543772f;
  return x > 0.f ? sc * x : sc * al * (__expf(x) - 1.f);
}

// ---- DPP row (16-lane) sum: every lane gets the sum of its 16-lane group ----
template <int CTRL>
__device__ __forceinline__ float dpp_add(float x) {
  union { float f; int i; } a, b;
  a.f = x;
  b.i = __builtin_amdgcn_update_dpp(a.i, a.i, CTRL, 0xF, 0xF, false);
  return x + b.f;
}
__device__ __forceinline__ float rowsum16(float x) {
  x = dpp_add<0x128>(x);  // row_ror:8
  x = dpp_add<0x124>(x);  // row_ror:4
  x = dpp_add<0x122>(x);  // row_ror:2
  x = dpp_add<0x121>(x);  // row_ror:1
  return x;
}
__device__ __forceinline__ f32x4 rowsum16x4(f32x4 v) {
  v[0] = rowsum16(v[0]); v[1] = rowsum16(v[1]);
  v[2] = rowsum16(v[2]); v[3] = rowsum16(v[3]);
  return v;
}

// ---- weight prep: fragment-ordered f16 + packed epilogue params (== R14) ----
__global__ __launch_bounds__(256) void prep_weights(
    const float* __restrict__ W_ih, const float* __restrict__ W_hh,
    const float* __restrict__ b_ih, const float* __restrict__ b_hh,
    const float* __restrict__ mW1, const float* __restrict__ mW2,
    const float* __restrict__ cW1, const float* __restrict__ cW2,
    const float* __restrict__ mg1w, const float* __restrict__ mg1b,
    const float* __restrict__ mg2w, const float* __restrict__ mg2b,
    const float* __restrict__ mWo, const float* __restrict__ W_se,
    const float* __restrict__ b_se,
    _Float16* __restrict__ Wg, _Float16* __restrict__ W1p, _Float16* __restrict__ W2p,
    _Float16* __restrict__ cW1p, _Float16* __restrict__ cW2p, float* __restrict__ bg,
    float* __restrict__ ppA, float* __restrict__ ppB, float* __restrict__ ppC) {
  int n = blockIdx.x * 256 + threadIdx.x;
  if (n < 81920) {
    int t16 = n / 2560, r = n % 2560;
    int ch = r / 512, l = (r >> 3) & 63, j = r & 7;
    int q = l >> 4, cl = l & 15;
    int cg = t16 >> 2, g = t16 & 3;            // cg-major tile order
    int row = g * 128 + cg * 16 + cl;          // gate-major output row
    int k = ch * 32 + q * 8 + j;
    float v = 0.f;
    if (k < 128) v = W_hh[row * 128 + k];
    else if (k < 144) v = W_ih[row * 16 + (k - 128)];
    Wg[n] = (_Float16)v;
    return;
  }
  n -= 81920;
  if (n < 98304) {
    int m = n >> 14, r = n & 16383;
    int ct = r >> 11, ch = (r >> 9) & 3, l = (r >> 3) & 63, j = r & 7;
    int q = l >> 4, cl = l & 15;
    int outcol = ct * 16 + cl, k = ch * 32 + q * 8 + j;
    W1p[n] = (_Float16)mW1[(m * 128 + k) * 128 + outcol];
    return;
  }
  n -= 98304;
  if (n < 98304) {
    int m = n >> 14, r = n & 16383;
    int ct = r >> 11, ch = (r >> 9) & 3, l = (r >> 3) & 63, j = r & 7;
    int q = l >> 4, cl = l & 15;
    int outcol = ct * 16 + cl, k = ch * 32 + q * 8 + j;
    W2p[n] = (_Float16)mW2[(m * 128 + k) * 128 + outcol];
    return;
  }
  n -= 98304;
  if (n < 16384) {
    int ct = n >> 11, ch = (n >> 9) & 3, l = (n >> 3) & 63, j = n & 7;
    int q = l >> 4, cl = l & 15;
    int outcol = ct * 16 + cl, k = ch * 32 + q * 8 + j;
    cW1p[n] = (_Float16)cW1[k * 128 + outcol];
    return;
  }
  n -= 16384;
  if (n < 16384) {
    int ct = n >> 11, ch = (n >> 9) & 3, l = (n >> 3) & 63, j = n & 7;
    int q = l >> 4, cl = l & 15;
    int outcol = ct * 16 + cl, k = ch * 32 + q * 8 + j;
    cW2p[n] = (_Float16)cW2[k * 128 + outcol];
    return;
  }
  n -= 16384;
  if (n < 512) { bg[n] = b_ih[n] + b_hh[n]; return; }
  n -= 512;
  if (n < 1536) {  // ppA
    int m = n >> 8, r = n & 255;
    int cl = r >> 4, k = r & 15;
    float v = (k < 8) ? mg1w[m * 128 + k * 16 + cl] : mg1b[m * 128 + (k - 8) * 16 + cl];
    ppA[n] = v;
    return;
  }
  n -= 1536;
  if (n < 3072) {  // ppB
    int m = n >> 9, r = n & 511;
    int cl = r >> 5, k = r & 31;
    int ct = k & 7, sel = k >> 3;
    float v;
    if (sel == 0)      v = mg2w[m * 128 + ct * 16 + cl];
    else if (sel == 1) v = mg2b[m * 128 + ct * 16 + cl];
    else               v = mWo[((size_t)m * 128 + ct * 16 + cl) * 2 + (sel - 2)];
    ppB[n] = v;
    return;
  }
  n -= 3072;
  if (n < 224) {  // ppC
    int g = n / 56, k = n % 56;
    float v = 0.f;
    if (k < 48)      v = W_se[(g * 4 + k / 12) * 12 + (k % 12)];
    else if (k < 52) v = b_se[g * 4 + (k - 48)];
    ppC[n] = v;
    return;
  }
}

// chunk schedule (32 chunks/step, same weights every step):
//   idx 0..7  : Wg + idx*10240, 20 x 1KB
//   idx 8..31 : j=idx-8, m=j>>2, r=j&3 -> (r<2?W1p:W2p)+m*16384+(r&1)*8192, 16 x 1KB
// 4 waves split the 1KB blocks of a chunk (i = w, w+4, ...).
__device__ __forceinline__ void stage_chunk(int idx, _Float16* dst, int w, int lane,
                                            const _Float16* __restrict__ Wg,
                                            const _Float16* __restrict__ W1p,
                                            const _Float16* __restrict__ W2p) {
  const _Float16* src;
  int nblk;
  if (idx < 8) {
    src = Wg + idx * 10240;
    nblk = 20;
  } else {
    int j = idx - 8, m = j >> 2, r = j & 3;
    src = ((r & 2) ? W2p : W1p) + m * 16384 + (r & 1) * 8192;
    nblk = 16;
  }
  for (int i = w; i < nblk; i += 4) {
    __builtin_amdgcn_global_load_lds(
        (const __attribute__((address_space(1))) void*)(src + i * 512 + lane * 8),
        (__attribute__((address_space(3))) void*)(dst + i * 512 + lane * 8),
        16, 0, 0);
  }
}

__device__ __forceinline__ f32x4 mfma16(f16x8 a, f16x8 b, f32x4 c) {
  return __builtin_amdgcn_mfma_f32_16x16x32_f16(a, b, c, 0, 0, 0);
}

// one half (4 col-tiles) of a 16x128 GEMM slice from a staged LDS buffer
__device__ __forceinline__ void gemm_half(const f16x8 (&a)[4], const _Float16* buf,
                                          int lane, f32x4 (&acc)[8], int base) {
#pragma unroll
  for (int ctl = 0; ctl < 4; ++ctl) {
    const _Float16* bp = buf + ctl * 2048 + lane * 8;
    f32x4 a0 = {0.f, 0.f, 0.f, 0.f};
#pragma unroll
    for (int ch = 0; ch < 4; ++ch) {
      f16x8 b = *(const f16x8*)(bp + ch * 512);
      a0 = mfma16(a[ch], b, a0);
    }
    acc[base + ctl] = a0;
  }
}

// ---- main decoder: 512 blocks x 4 waves; wave owns 16 rows end-to-end ----
__global__ __launch_bounds__(256, 2) void mmdec_main(
    const float* __restrict__ last_obs_rel, const float* __restrict__ h0, const float* __restrict__ c0,
    const float* __restrict__ mbo, const float* __restrict__ cg1w, const float* __restrict__ cg1b,
    const float* __restrict__ cg2w, const float* __restrict__ cg2b,
    const float* __restrict__ cWo, const float* __restrict__ cbo,
    const _Float16* __restrict__ Wg, const _Float16* __restrict__ W1p, const _Float16* __restrict__ W2p,
    const _Float16* __restrict__ cW1p, const _Float16* __restrict__ cW2p, const float* __restrict__ bgp,
    const float* __restrict__ ppA, const float* __restrict__ ppB, const float* __restrict__ ppC,
    float* __restrict__ out) {
  // LDS map (bytes): stage 2x20480 | h 64x320 | t1 64x272 | rel 64x12 f32
  __shared__ __align__(16) unsigned char smem[81920];
  _Float16* stage0 = (_Float16*)smem;                       // [0, 40960)
  unsigned char* h_base = smem + 40960;                     // [40960, 61440)
  unsigned char* t1_base = smem + 61440;                    // [61440, 78848)
  float* rel_all = (float*)(smem + 78848);                  // [78848, 81920)

  const int tid = threadIdx.x;
  const int w = tid >> 6;       // wave id 0..3: owns rows [16w, 16w+16) of block
  const int lane = tid & 63;
  const int q = lane >> 4, cl = lane & 15;
  const int rowbase = blockIdx.x * 64 + w * 16;             // wave's first global row

  auto hrow = [&](int r) -> _Float16* { return (_Float16*)(h_base + (w * 16 + r) * 320); };
  auto t1row = [&](int r) -> _Float16* { return (_Float16*)(t1_base + (w * 16 + r) * 272); };
  float* relw = rel_all + w * 16 * 12;

  auto sbuf = [&](int idx) -> _Float16* { return stage0 + ((idx & 1) ? 10240 : 0); };

  // ---- init: h0 -> LDS f16 (quarter row per lane, float4 loads) ----
  {
    const int rr = lane & 15, seg = lane >> 4;
    const float* src = h0 + (size_t)(rowbase + rr) * HD + seg * 32;
    _Float16* dst = hrow(rr) + seg * 32;
#pragma unroll
    for (int i = 0; i < 32; i += 8) {
      f32x4 a = *(const f32x4*)(src + i);
      f32x4 b = *(const f32x4*)(src + i + 4);
      f16x8 v;
#pragma unroll
      for (int k = 0; k < 4; ++k) { v[k] = (_Float16)a[k]; v[4 + k] = (_Float16)b[k]; }
      *(f16x8*)(dst + i) = v;
    }
    // x = selu(tile(last_obs_rel,6) @ W_se.T + b_se); 4 E-cols per lane
    const float r0 = last_obs_rel[(size_t)(rowbase + rr) * 2 + 0];
    const float r1 = last_obs_rel[(size_t)(rowbase + rr) * 2 + 1];
    const int e0 = seg * 4;
    f16x4 v;
#pragma unroll
    for (int i = 0; i < 4; ++i) {
      float acc = ppC[seg * 56 + 48 + i];
#pragma unroll
      for (int j = 0; j < 12; ++j) acc += ((j & 1) ? r1 : r0) * ppC[seg * 56 + i * 12 + j];
      v[i] = (_Float16)selu_(acc);
    }
    *(f16x4*)(hrow(rr) + 128 + e0) = v;
    if (lane < 16) {  // zero pad cols 144..159
      f16x8 z;
#pragma unroll
      for (int i = 0; i < 8; ++i) z[i] = (_Float16)0.f;
      *(f16x8*)(hrow(lane) + 144) = z;
      *(f16x8*)(hrow(lane) + 152) = z;
    }
  }
  // ---- init: c0 in C-layout regs [cg] ----
  f32x4 cacc[8];
#pragma unroll
  for (int cg = 0; cg < 8; ++cg)
#pragma unroll
    for (int r = 0; r < 4; ++r)
      cacc[cg][r] = c0[(size_t)(rowbase + q * 4 + r) * HD + cg * 16 + cl];
  float bgh[8][4];
#pragma unroll
  for (int cg = 0; cg < 8; ++cg)
#pragma unroll
    for (int g = 0; g < 4; ++g) bgh[cg][g] = bgp[g * 128 + cg * 16 + cl];
  f32x4 hc[8];  // h(t) in C-layout (residual source)

  // ---- batched out-store precompute: 96 (row,mode) pairs per wave ----
  const int pA_ = lane, pB_ = 64 + lane;
  const size_t obA = ((size_t)(rowbase + pA_ / 6) * MM + pA_ % 6) * TT;
  const size_t obB = ((size_t)(rowbase + pB_ / 6) * MM + pB_ % 6) * TT;
  const int rlA = (pA_ / 6) * 12 + (pA_ % 6) * 2;
  const int rlB = (pB_ / 6) * 12 + (pB_ % 6) * 2;

  // step-tail W_se pack pointer (per-lane e0 group)
  const float* wsp = ppC + (lane >> 4) * 56;

  // prime the pipeline: stage chunk 0
  stage_chunk(0, sbuf(0), w, lane, Wg, W1p, W2p);
  __syncthreads();

  const size_t confbase = (size_t)B_ROWS * MM * TT * 2;

  for (int t = 0; t < TT; ++t) {
    // ======== LSTM: [h|x|0](K=160) @ Wg^T; c update; h(t) scatter ========
    f16x8 afr[5];
#pragma unroll
    for (int ch = 0; ch < 5; ++ch)
      afr[ch] = *(const f16x8*)(hrow(cl) + ch * 32 + q * 8);

    for (int cg = 0; cg < 8; ++cg) {  // chunk idx = cg; contains gates i,f,g,o for cg
      stage_chunk((cg + 1) & 31, sbuf(cg + 1), w, lane, Wg, W1p, W2p);
      const _Float16* buf = sbuf(cg);
      f32x4 gacc[4];
#pragma unroll
      for (int g = 0; g < 4; ++g) gacc[g] = f32x4{0.f, 0.f, 0.f, 0.f};
#pragma unroll
      for (int g = 0; g < 4; ++g) {
        const _Float16* bp = buf + g * 2560 + lane * 8;
#pragma unroll
        for (int ch = 0; ch < 5; ++ch) {
          f16x8 b = *(const f16x8*)(bp + ch * 512);
          gacc[g] = mfma16(afr[ch], b, gacc[g]);
        }
      }
#pragma unroll
      for (int r = 0; r < 4; ++r) {
        const float iv = sigm(gacc[0][r] + bgh[cg][0]);
        const float fv = sigm(gacc[1][r] + bgh[cg][1]);
        const float gv = tanhf_(gacc[2][r] + bgh[cg][2]);
        const float ov = sigm(gacc[3][r] + bgh[cg][3]);
        const float cn = fv * cacc[cg][r] + iv * gv;
        cacc[cg][r] = cn;
        const float hv = ov * tanhf_(cn);
        hc[cg][r] = hv;
        hrow(q * 4 + r)[cg * 16 + cl] = (_Float16)hv;
      }
      __syncthreads();
    }

    // ======== 6 mode heads: shared gemm code for gemm1/gemm2 (gg loop) ========
    f16x8 frag[4];
#pragma unroll
    for (int ch = 0; ch < 4; ++ch)
      frag[ch] = *(const f16x8*)(hrow(cl) + ch * 32 + q * 8);

    for (int m = 0; m < MM; ++m) {
      const int base = 8 + m * 4;
      // GN1 params: vector loads issued early; next barrier drains them free
      const float* pAv = ppA + (m * 16 + cl) * 16;
      const f32x4 g1wA = *(const f32x4*)(pAv);
      const f32x4 g1wB = *(const f32x4*)(pAv + 4);
      const f32x4 g1bA = *(const f32x4*)(pAv + 8);
      const f32x4 g1bB = *(const f32x4*)(pAv + 12);
      f32x4 g2wA, g2wB, g2bA, g2bB, w0A, w0B, w1A, w1B;

      f16x8 A[4];
#pragma unroll
      for (int ch = 0; ch < 4; ++ch) A[ch] = frag[ch];

      for (int gg = 0; gg < 2; ++gg) {
        const int cb = base + gg * 2;
        f32x4 accv[8];
        stage_chunk((cb + 1) & 31, sbuf(cb + 1), w, lane, Wg, W1p, W2p);
        gemm_half(A, sbuf(cb), lane, accv, 0);
        __syncthreads();
        stage_chunk((cb + 2) & 31, sbuf(cb + 2), w, lane, Wg, W1p, W2p);
        gemm_half(A, sbuf(cb + 1), lane, accv, 4);
        // shared GN statistics (DPP rowsum)
        f32x4 mean, rstd;
        {
          f32x4 s1 = {0.f, 0.f, 0.f, 0.f}, s2 = {0.f, 0.f, 0.f, 0.f};
#pragma unroll
          for (int ct = 0; ct < 8; ++ct) { s1 += accv[ct]; s2 += accv[ct] * accv[ct]; }
          s1 = rowsum16x4(s1); s2 = rowsum16x4(s2);
          mean = s1 * (1.f / 128.f);
#pragma unroll
          for (int r = 0; r < 4; ++r)
            rstd[r] = rsqrtf(s2[r] * (1.f / 128.f) - mean[r] * mean[r] + 1e-5f);
        }
        if (gg == 0) {
          // GN1 + relu -> t1 (overlaps the staged load)
#pragma unroll
          for (int ct = 0; ct < 8; ++ct) {
            const float g1 = (ct < 4) ? g1wA[ct & 3] : g1wB[ct & 3];
            const float b1 = (ct < 4) ? g1bA[ct & 3] : g1bB[ct & 3];
#pragma unroll
            for (int r = 0; r < 4; ++r) {
              float v = (accv[ct][r] - mean[r]) * rstd[r] * g1 + b1;
              t1row(q * 4 + r)[ct * 16 + cl] = (_Float16)fmaxf(v, 0.f);
            }
          }
          __syncthreads();
          // GN2/out-proj params early (drained by next barrier)
          const float* pBv = ppB + (m * 16 + cl) * 32;
          g2wA = *(const f32x4*)(pBv);
          g2wB = *(const f32x4*)(pBv + 4);
          g2bA = *(const f32x4*)(pBv + 8);
          g2bB = *(const f32x4*)(pBv + 12);
          w0A  = *(const f32x4*)(pBv + 16);
          w0B  = *(const f32x4*)(pBv + 20);
          w1A  = *(const f32x4*)(pBv + 24);
          w1B  = *(const f32x4*)(pBv + 28);
          // A <- t1 fragment (same-wave LDS write->read is in-order)
#pragma unroll
          for (int ch = 0; ch < 4; ++ch)
            A[ch] = *(const f16x8*)(t1row(cl) + ch * 32 + q * 8);
        } else {
          // GN2 + residual (hc regs) + out-proj
          f32x4 po0 = {0.f, 0.f, 0.f, 0.f}, po1 = {0.f, 0.f, 0.f, 0.f};
#pragma unroll
          for (int ct = 0; ct < 8; ++ct) {
            const float g2 = (ct < 4) ? g2wA[ct & 3] : g2wB[ct & 3];
            const float b2 = (ct < 4) ? g2bA[ct & 3] : g2bB[ct & 3];
            const float w0 = (ct < 4) ? w0A[ct & 3] : w0B[ct & 3];
            const float w1 = (ct < 4) ? w1A[ct & 3] : w1B[ct & 3];
#pragma unroll
            for (int r = 0; r < 4; ++r) {
              float v = (accv[ct][r] - mean[r]) * rstd[r] * g2 + b2 + hc[ct][r];
              v = fmaxf(v, 0.f);
              po0[r] += v * w0;
              po1[r] += v * w1;
            }
          }
          po0 = rowsum16x4(po0);
          po1 = rowsum16x4(po1);
          if (cl < 2) {
#pragma unroll
            for (int r = 0; r < 4; ++r) {
              const int rl_ = q * 4 + r;
              relw[rl_ * 12 + m * 2 + cl] = (cl ? po1[r] : po0[r]) + mbo[m * 2 + cl];
            }
          }
          __syncthreads();
        }
      }
    }

    // ======== step tail: batched out stores + xin (all wave-local) ========
    {
      float2 vA;
      vA.x = relw[rlA]; vA.y = relw[rlA + 1];
      *(float2*)(out + (obA + t) * 2) = vA;
      if (lane < 32) {
        float2 vB;
        vB.x = relw[rlB]; vB.y = relw[rlB + 1];
        *(float2*)(out + (obB + t) * 2) = vB;
      }
    }
    {
      const int rr = lane & 15;
      const f32x4 rl0 = *(const f32x4*)(relw + rr * 12);
      const f32x4 rl1 = *(const f32x4*)(relw + rr * 12 + 4);
      const f32x4 rl2 = *(const f32x4*)(relw + rr * 12 + 8);
      f32x4 wv0, wv1, wv2, bsv;
      bsv = *(const f32x4*)(wsp + 48);
      f16x4 v;
#pragma unroll
      for (int i = 0; i < 4; ++i) {
        wv0 = *(const f32x4*)(wsp + i * 12);
        wv1 = *(const f32x4*)(wsp + i * 12 + 4);
        wv2 = *(const f32x4*)(wsp + i * 12 + 8);
        float acc = bsv[i];
#pragma unroll
        for (int j = 0; j < 4; ++j) acc += rl0[j] * wv0[j];
#pragma unroll
        for (int j = 0; j < 4; ++j) acc += rl1[j] * wv1[j];
#pragma unroll
        for (int j = 0; j < 4; ++j) acc += rl2[j] * wv2[j];
        v[i] = (_Float16)selu_(acc);
      }
      *(f16x4*)(hrow(rr) + 128 + (lane >> 4) * 4) = v;
    }
    // no barrier: h/x/rel are wave-private; staging WAR is covered by the
    // mode-5 sync above (next overwrite of that buffer is 2 chunks away)
  }

  // ======== confidence head on hT (wave-local; weights from global) ========
  {
    f16x8 frag[4];
#pragma unroll
    for (int ch = 0; ch < 4; ++ch)
      frag[ch] = *(const f16x8*)(hrow(cl) + ch * 32 + q * 8);
    f32x4 acc1[8];
#pragma unroll
    for (int ct = 0; ct < 8; ++ct) {
      const _Float16* bp = cW1p + ct * 2048 + lane * 8;
      f32x4 a0 = {0.f, 0.f, 0.f, 0.f};
#pragma unroll
      for (int ch = 0; ch < 4; ++ch) {
        f16x8 b = *(const f16x8*)(bp + ch * 512);
        a0 = mfma16(frag[ch], b, a0);
      }
      acc1[ct] = a0;
    }
    f32x4 mean, rstd;
    {
      f32x4 s1 = {0.f, 0.f, 0.f, 0.f}, s2 = {0.f, 0.f, 0.f, 0.f};
#pragma unroll
      for (int ct = 0; ct < 8; ++ct) { s1 += acc1[ct]; s2 += acc1[ct] * acc1[ct]; }
      s1 = rowsum16x4(s1); s2 = rowsum16x4(s2);
      mean = s1 * (1.f / 128.f);
#pragma unroll
      for (int r = 0; r < 4; ++r)
        rstd[r] = rsqrtf(s2[r] * (1.f / 128.f) - mean[r] * mean[r] + 1e-5f);
    }
#pragma unroll
    for (int ct = 0; ct < 8; ++ct) {
      const float g1 = cg1w[ct * 16 + cl];
      const float b1 = cg1b[ct * 16 + cl];
#pragma unroll
      for (int r = 0; r < 4; ++r) {
        float v = (acc1[ct][r] - mean[r]) * rstd[r] * g1 + b1;
        t1row(q * 4 + r)[ct * 16 + cl] = (_Float16)fmaxf(v, 0.f);
      }
    }
    f16x8 at1[4];
#pragma unroll
    for (int ch = 0; ch < 4; ++ch)
      at1[ch] = *(const f16x8*)(t1row(cl) + ch * 32 + q * 8);
    f32x4 acc2[8];
#pragma unroll
    for (int ct = 0; ct < 8; ++ct) {
      const _Float16* bp = cW2p + ct * 2048 + lane * 8;
      f32x4 a0 = {0.f, 0.f, 0.f, 0.f};
#pragma unroll
      for (int ch = 0; ch < 4; ++ch) {
        f16x8 b = *(const f16x8*)(bp + ch * 512);
        a0 = mfma16(at1[ch], b, a0);
      }
      acc2[ct] = a0;
    }
    f32x4 mean2, rstd2;
    {
      f32x4 s1 = {0.f, 0.f, 0.f, 0.f}, s2 = {0.f, 0.f, 0.f, 0.f};
#pragma unroll
      for (int ct = 0; ct < 8; ++ct) { s1 += acc2[ct]; s2 += acc2[ct] * acc2[ct]; }
      s1 = rowsum16x4(s1); s2 = rowsum16x4(s2);
      mean2 = s1 * (1.f / 128.f);
#pragma unroll
      for (int r = 0; r < 4; ++r)
        rstd2[r] = rsqrtf(s2[r] * (1.f / 128.f) - mean2[r] * mean2[r] + 1e-5f);
    }
    float pl[4][6];
#pragma unroll
    for (int r = 0; r < 4; ++r)
#pragma unroll
      for (int k = 0; k < 6; ++k) pl[r][k] = 0.f;
#pragma unroll
    for (int ct = 0; ct < 8; ++ct) {
      const float g2 = cg2w[ct * 16 + cl];
      const float b2 = cg2b[ct * 16 + cl];
      float wo[6];
#pragma unroll
      for (int k = 0; k < 6; ++k) wo[k] = cWo[(ct * 16 + cl) * 6 + k];
#pragma unroll
      for (int r = 0; r < 4; ++r) {
        float v = (acc2[ct][r] - mean2[r]) * rstd2[r] * g2 + b2 + hc[ct][r];
        v = fmaxf(v, 0.f);
#pragma unroll
        for (int k = 0; k < 6; ++k) pl[r][k] += v * wo[k];
      }
    }
#pragma unroll
    for (int r = 0; r < 4; ++r)
#pragma unroll
      for (int k = 0; k < 6; ++k) pl[r][k] = rowsum16(pl[r][k]);
    if (cl == 0) {
#pragma unroll
      for (int r = 0; r < 4; ++r) {
        float l[6];
#pragma unroll
        for (int k = 0; k < 6; ++k) l[k] = pl[r][k] + cbo[k];
        float mx = l[0];
#pragma unroll
        for (int k = 1; k < 6; ++k) mx = fmaxf(mx, l[k]);
        float s = 0.f;
#pragma unroll
        for (int k = 0; k < 6; ++k) { l[k] = __expf(l[k] - mx); s += l[k]; }
        const float inv = fast_rcp(s);
#pragma unroll
        for (int k = 0; k < 6; ++k)
          out[confbase + (size_t)(rowbase + q * 4 + r) * 6 + k] = l[k] * inv;
      }
    }
  }
}

extern "C" void kernel_launch(void* const* d_in, const int* in_sizes, int n_in,
                              void* d_out, int out_size, void* d_ws, size_t ws_size,
                              hipStream_t stream) {
  (void)in_sizes; (void)n_in; (void)out_size; (void)ws_size;
  const float* last_obs_rel = (const float*)d_in[1];
  const float* h0   = (const float*)d_in[2];
  const float* c0   = (const float*)d_in[3];
  const float* W_se = (const float*)d_in[4];
  const float* b_se = (const float*)d_in[5];
  const float* W_ih = (const float*)d_in[6];
  const float* W_hh = (const float*)d_in[7];
  const float* b_ih = (const float*)d_in[8];
  const float* b_hh = (const float*)d_in[9];
  const float* mW1  = (const float*)d_in[10];
  const float* mg1w = (const float*)d_in[11];
  const float* mg1b = (const float*)d_in[12];
  const float* mW2  = (const float*)d_in[13];
  const float* mg2w = (const float*)d_in[14];
  const float* mg2b = (const float*)d_in[15];
  const float* mWo  = (const float*)d_in[16];
  const float* mbo  = (const float*)d_in[17];
  const float* cW1  = (const float*)d_in[18];
  const float* cg1w = (const float*)d_in[19];
  const float* cg1b = (const float*)d_in[20];
  const float* cW2  = (const float*)d_in[21];
  const float* cg2w = (const float*)d_in[22];
  const float* cg2b = (const float*)d_in[23];
  const float* cWo  = (const float*)d_in[24];
  const float* cbo  = (const float*)d_in[25];

  char* ws = (char*)d_ws;
  _Float16* Wg   = (_Float16*)(ws + 0);       // 512*160 f16   = 163840 B
  _Float16* W1p  = (_Float16*)(ws + 163840);  // 6*128*128 f16 = 196608 B
  _Float16* W2p  = (_Float16*)(ws + 360448);  // 6*128*128 f16 = 196608 B
  _Float16* cW1p = (_Float16*)(ws + 557056);  // 128*128 f16   =  32768 B
  _Float16* cW2p = (_Float16*)(ws + 589824);  // 128*128 f16   =  32768 B
  float*    bg   = (float*)   (ws + 622592);  // 512 f32       =   2048 B
  float*    ppA  = (float*)   (ws + 624640);  // 1536 f32      =   6144 B
  float*    ppB  = (float*)   (ws + 630784);  // 3072 f32      =  12288 B
  float*    ppC  = (float*)   (ws + 643072);  // 224 f32       =    896 B

  prep_weights<<<1237, 256, 0, stream>>>(W_ih, W_hh, b_ih, b_hh, mW1, mW2, cW1, cW2,
                                         mg1w, mg1b, mg2w, mg2b, mWo, W_se, b_se,
                                         Wg, W1p, W2p, cW1p, cW2p, bg, ppA, ppB, ppC);
  mmdec_main<<<B_ROWS / 64, 256, 0, stream>>>(last_obs_rel, h0, c0,
                                              mbo, cg1w, cg1b, cg2w, cg2b, cWo, cbo,
                                              Wg, W1p, W2p, cW1p, cW2p, bg,
                                              ppA, ppB, ppC, (float*)d_out);
}

// Round 12
// 1735.823 us; speedup vs baseline: 1.1343x; 1.1069x over previous
//
#include <hip/hip_runtime.h>
#include <hip/hip_bf16.h>
#include <cstdint>
#include <cstddef>

// MMDecoderDoubleBranch R18 = R14 (verified best 1702us) + 6-step shift-register
// output buffering. R17 refuted the pure-I$ theory (smaller body, FETCH UP);
// reverted its fold. R14 accounting: MFMA 13% (~floor), LDS ~40-45%
// (irreducible at 16 rows/wave), VALU ~25%. Remaining clean mechanism: out
// stores are 1 scattered 8B float2/lane/step -> each 64B line written
// partially 6x with RMW fetches (WRITE 222MB vs ~50MB useful). Fix: buffer 6
// steps per lane in NAMED float2 regs (compile-time indices only, rule #20:
// no runtime-indexed arrays), flush 48B of one line back-to-back at t%6==5 ->
// L2 merges to ~1 line-write. +24 VGPR, no sync/structure change; everything
// else byte-identical to R14 (32 chunks/step, 2x20KB stage + syncthreads,
// DPP rowsum GN, packed params ppA/ppB/ppC, rolled loops, 81920B LDS,
// 2 blocks/CU).

#define HD 128
#define TT 30
#define MM 6
#define B_ROWS 32768

typedef _Float16 f16x8 __attribute__((ext_vector_type(8)));
typedef _Float16 f16x4 __attribute__((ext_vector_type(4)));
typedef float f32x4 __attribute__((ext_vector_type(4)));

__device__ __forceinline__ float fast_rcp(float x) { return __builtin_amdgcn_rcpf(x); }
__device__ __forceinline__ float sigm(float x) { return fast_rcp(1.f + __expf(-x)); }
__device__ __forceinline__ float tanhf_(float x) { return 1.f - 2.f * fast_rcp(__expf(2.f * x) + 1.f); }
__device__ __forceinline__ float selu_(float x) {
  const float sc = 1.0507009873554805f;
  const float al = 1.6732632423543772f;
  return x > 0.f ? sc * x : sc * al * (__expf(x) - 1.f);
}

// ---- DPP row (16-lane) sum: every lane gets the sum of its 16-lane group ----
template <int CTRL>
__device__ __forceinline__ float dpp_add(float x) {
  union { float f; int i; } a, b;
  a.f = x;
  b.i = __builtin_amdgcn_update_dpp(a.i, a.i, CTRL, 0xF, 0xF, false);
  return x + b.f;
}
__device__ __forceinline__ float rowsum16(float x) {
  x = dpp_add<0x128>(x);  // row_ror:8
  x = dpp_add<0x124>(x);  // row_ror:4
  x = dpp_add<0x122>(x);  // row_ror:2
  x = dpp_add<0x121>(x);  // row_ror:1
  return x;
}
__device__ __forceinline__ f32x4 rowsum16x4(f32x4 v) {
  v[0] = rowsum16(v[0]); v[1] = rowsum16(v[1]);
  v[2] = rowsum16(v[2]); v[3] = rowsum16(v[3]);
  return v;
}

// ---- weight prep: fragment-ordered f16 + packed epilogue params (== R14) ----
__global__ __launch_bounds__(256) void prep_weights(
    const float* __restrict__ W_ih, const float* __restrict__ W_hh,
    const float* __restrict__ b_ih, const float* __restrict__ b_hh,
    const float* __restrict__ mW1, const float* __restrict__ mW2,
    const float* __restrict__ cW1, const float* __restrict__ cW2,
    const float* __restrict__ mg1w, const float* __restrict__ mg1b,
    const float* __restrict__ mg2w, const float* __restrict__ mg2b,
    const float* __restrict__ mWo, const float* __restrict__ W_se,
    const float* __restrict__ b_se,
    _Float16* __restrict__ Wg, _Float16* __restrict__ W1p, _Float16* __restrict__ W2p,
    _Float16* __restrict__ cW1p, _Float16* __restrict__ cW2p, float* __restrict__ bg,
    float* __restrict__ ppA, float* __restrict__ ppB, float* __restrict__ ppC) {
  int n = blockIdx.x * 256 + threadIdx.x;
  if (n < 81920) {
    int t16 = n / 2560, r = n % 2560;
    int ch = r / 512, l = (r >> 3) & 63, j = r & 7;
    int q = l >> 4, cl = l & 15;
    int cg = t16 >> 2, g = t16 & 3;            // cg-major tile order
    int row = g * 128 + cg * 16 + cl;          // gate-major output row
    int k = ch * 32 + q * 8 + j;
    float v = 0.f;
    if (k < 128) v = W_hh[row * 128 + k];
    else if (k < 144) v = W_ih[row * 16 + (k - 128)];
    Wg[n] = (_Float16)v;
    return;
  }
  n -= 81920;
  if (n < 98304) {
    int m = n >> 14, r = n & 16383;
    int ct = r >> 11, ch = (r >> 9) & 3, l = (r >> 3) & 63, j = r & 7;
    int q = l >> 4, cl = l & 15;
    int outcol = ct * 16 + cl, k = ch * 32 + q * 8 + j;
    W1p[n] = (_Float16)mW1[(m * 128 + k) * 128 + outcol];
    return;
  }
  n -= 98304;
  if (n < 98304) {
    int m = n >> 14, r = n & 16383;
    int ct = r >> 11, ch = (r >> 9) & 3, l = (r >> 3) & 63, j = r & 7;
    int q = l >> 4, cl = l & 15;
    int outcol = ct * 16 + cl, k = ch * 32 + q * 8 + j;
    W2p[n] = (_Float16)mW2[(m * 128 + k) * 128 + outcol];
    return;
  }
  n -= 98304;
  if (n < 16384) {
    int ct = n >> 11, ch = (n >> 9) & 3, l = (n >> 3) & 63, j = n & 7;
    int q = l >> 4, cl = l & 15;
    int outcol = ct * 16 + cl, k = ch * 32 + q * 8 + j;
    cW1p[n] = (_Float16)cW1[k * 128 + outcol];
    return;
  }
  n -= 16384;
  if (n < 16384) {
    int ct = n >> 11, ch = (n >> 9) & 3, l = (n >> 3) & 63, j = n & 7;
    int q = l >> 4, cl = l & 15;
    int outcol = ct * 16 + cl, k = ch * 32 + q * 8 + j;
    cW2p[n] = (_Float16)cW2[k * 128 + outcol];
    return;
  }
  n -= 16384;
  if (n < 512) { bg[n] = b_ih[n] + b_hh[n]; return; }
  n -= 512;
  if (n < 1536) {  // ppA
    int m = n >> 8, r = n & 255;
    int cl = r >> 4, k = r & 15;
    float v = (k < 8) ? mg1w[m * 128 + k * 16 + cl] : mg1b[m * 128 + (k - 8) * 16 + cl];
    ppA[n] = v;
    return;
  }
  n -= 1536;
  if (n < 3072) {  // ppB
    int m = n >> 9, r = n & 511;
    int cl = r >> 5, k = r & 31;
    int ct = k & 7, sel = k >> 3;
    float v;
    if (sel == 0)      v = mg2w[m * 128 + ct * 16 + cl];
    else if (sel == 1) v = mg2b[m * 128 + ct * 16 + cl];
    else               v = mWo[((size_t)m * 128 + ct * 16 + cl) * 2 + (sel - 2)];
    ppB[n] = v;
    return;
  }
  n -= 3072;
  if (n < 224) {  // ppC
    int g = n / 56, k = n % 56;
    float v = 0.f;
    if (k < 48)      v = W_se[(g * 4 + k / 12) * 12 + (k % 12)];
    else if (k < 52) v = b_se[g * 4 + (k - 48)];
    ppC[n] = v;
    return;
  }
}

// chunk schedule (32 chunks/step, same weights every step):
//   idx 0..7  : Wg + idx*10240, 20 x 1KB
//   idx 8..31 : j=idx-8, m=j>>2, r=j&3 -> (r<2?W1p:W2p)+m*16384+(r&1)*8192, 16 x 1KB
// 4 waves split the 1KB blocks of a chunk (i = w, w+4, ...).
__device__ __forceinline__ void stage_chunk(int idx, _Float16* dst, int w, int lane,
                                            const _Float16* __restrict__ Wg,
                                            const _Float16* __restrict__ W1p,
                                            const _Float16* __restrict__ W2p) {
  const _Float16* src;
  int nblk;
  if (idx < 8) {
    src = Wg + idx * 10240;
    nblk = 20;
  } else {
    int j = idx - 8, m = j >> 2, r = j & 3;
    src = ((r & 2) ? W2p : W1p) + m * 16384 + (r & 1) * 8192;
    nblk = 16;
  }
  for (int i = w; i < nblk; i += 4) {
    __builtin_amdgcn_global_load_lds(
        (const __attribute__((address_space(1))) void*)(src + i * 512 + lane * 8),
        (__attribute__((address_space(3))) void*)(dst + i * 512 + lane * 8),
        16, 0, 0);
  }
}

__device__ __forceinline__ f32x4 mfma16(f16x8 a, f16x8 b, f32x4 c) {
  return __builtin_amdgcn_mfma_f32_16x16x32_f16(a, b, c, 0, 0, 0);
}

// one half (4 col-tiles) of a 16x128 GEMM slice from a staged LDS buffer
__device__ __forceinline__ void gemm_half(const f16x8 (&a)[4], const _Float16* buf,
                                          int lane, f32x4 (&acc)[8], int base) {
#pragma unroll
  for (int ctl = 0; ctl < 4; ++ctl) {
    const _Float16* bp = buf + ctl * 2048 + lane * 8;
    f32x4 a0 = {0.f, 0.f, 0.f, 0.f};
#pragma unroll
    for (int ch = 0; ch < 4; ++ch) {
      f16x8 b = *(const f16x8*)(bp + ch * 512);
      a0 = mfma16(a[ch], b, a0);
    }
    acc[base + ctl] = a0;
  }
}

// ---- main decoder: 512 blocks x 4 waves; wave owns 16 rows end-to-end ----
__global__ __launch_bounds__(256, 2) void mmdec_main(
    const float* __restrict__ last_obs_rel, const float* __restrict__ h0, const float* __restrict__ c0,
    const float* __restrict__ mbo, const float* __restrict__ cg1w, const float* __restrict__ cg1b,
    const float* __restrict__ cg2w, const float* __restrict__ cg2b,
    const float* __restrict__ cWo, const float* __restrict__ cbo,
    const _Float16* __restrict__ Wg, const _Float16* __restrict__ W1p, const _Float16* __restrict__ W2p,
    const _Float16* __restrict__ cW1p, const _Float16* __restrict__ cW2p, const float* __restrict__ bgp,
    const float* __restrict__ ppA, const float* __restrict__ ppB, const float* __restrict__ ppC,
    float* __restrict__ out) {
  // LDS map (bytes): stage 2x20480 | h 64x320 | t1 64x272 | rel 64x12 f32
  __shared__ __align__(16) unsigned char smem[81920];
  _Float16* stage0 = (_Float16*)smem;                       // [0, 40960)
  unsigned char* h_base = smem + 40960;                     // [40960, 61440)
  unsigned char* t1_base = smem + 61440;                    // [61440, 78848)
  float* rel_all = (float*)(smem + 78848);                  // [78848, 81920)

  const int tid = threadIdx.x;
  const int w = tid >> 6;       // wave id 0..3: owns rows [16w, 16w+16) of block
  const int lane = tid & 63;
  const int q = lane >> 4, cl = lane & 15;
  const int rowbase = blockIdx.x * 64 + w * 16;             // wave's first global row

  auto hrow = [&](int r) -> _Float16* { return (_Float16*)(h_base + (w * 16 + r) * 320); };
  auto t1row = [&](int r) -> _Float16* { return (_Float16*)(t1_base + (w * 16 + r) * 272); };
  float* relw = rel_all + w * 16 * 12;

  auto sbuf = [&](int idx) -> _Float16* { return stage0 + ((idx & 1) ? 10240 : 0); };

  // ---- init: h0 -> LDS f16 (quarter row per lane, float4 loads) ----
  {
    const int rr = lane & 15, seg = lane >> 4;
    const float* src = h0 + (size_t)(rowbase + rr) * HD + seg * 32;
    _Float16* dst = hrow(rr) + seg * 32;
#pragma unroll
    for (int i = 0; i < 32; i += 8) {
      f32x4 a = *(const f32x4*)(src + i);
      f32x4 b = *(const f32x4*)(src + i + 4);
      f16x8 v;
#pragma unroll
      for (int k = 0; k < 4; ++k) { v[k] = (_Float16)a[k]; v[4 + k] = (_Float16)b[k]; }
      *(f16x8*)(dst + i) = v;
    }
    // x = selu(tile(last_obs_rel,6) @ W_se.T + b_se); 4 E-cols per lane
    const float r0 = last_obs_rel[(size_t)(rowbase + rr) * 2 + 0];
    const float r1 = last_obs_rel[(size_t)(rowbase + rr) * 2 + 1];
    const int e0 = seg * 4;
    f16x4 v;
#pragma unroll
    for (int i = 0; i < 4; ++i) {
      float acc = ppC[seg * 56 + 48 + i];
#pragma unroll
      for (int j = 0; j < 12; ++j) acc += ((j & 1) ? r1 : r0) * ppC[seg * 56 + i * 12 + j];
      v[i] = (_Float16)selu_(acc);
    }
    *(f16x4*)(hrow(rr) + 128 + e0) = v;
    if (lane < 16) {  // zero pad cols 144..159
      f16x8 z;
#pragma unroll
      for (int i = 0; i < 8; ++i) z[i] = (_Float16)0.f;
      *(f16x8*)(hrow(lane) + 144) = z;
      *(f16x8*)(hrow(lane) + 152) = z;
    }
  }
  // ---- init: c0 in C-layout regs [cg] ----
  f32x4 cacc[8];
#pragma unroll
  for (int cg = 0; cg < 8; ++cg)
#pragma unroll
    for (int r = 0; r < 4; ++r)
      cacc[cg][r] = c0[(size_t)(rowbase + q * 4 + r) * HD + cg * 16 + cl];
  float bgh[8][4];
#pragma unroll
  for (int cg = 0; cg < 8; ++cg)
#pragma unroll
    for (int g = 0; g < 4; ++g) bgh[cg][g] = bgp[g * 128 + cg * 16 + cl];
  f32x4 hc[8];  // h(t) in C-layout (residual source)

  // ---- batched out-store precompute: 96 (row,mode) pairs per wave ----
  const int pA_ = lane, pB_ = 64 + lane;
  const size_t obA = ((size_t)(rowbase + pA_ / 6) * MM + pA_ % 6) * TT;
  const size_t obB = ((size_t)(rowbase + pB_ / 6) * MM + pB_ % 6) * TT;
  const int rlA = (pA_ / 6) * 12 + (pA_ % 6) * 2;
  const int rlB = (lane < 32) ? ((pB_ / 6) * 12 + (pB_ % 6) * 2) : 0;  // safe idx

  // 6-step output shift registers (named slots only; rule #20)
  float2 bA0, bA1, bA2, bA3, bA4, bA5;
  float2 bB0, bB1, bB2, bB3, bB4, bB5;

  // step-tail W_se pack pointer (per-lane e0 group)
  const float* wsp = ppC + (lane >> 4) * 56;

  // prime the pipeline: stage chunk 0
  stage_chunk(0, sbuf(0), w, lane, Wg, W1p, W2p);
  __syncthreads();

  const size_t confbase = (size_t)B_ROWS * MM * TT * 2;

  for (int t = 0; t < TT; ++t) {
    // ======== LSTM: [h|x|0](K=160) @ Wg^T; c update; h(t) scatter ========
    f16x8 afr[5];
#pragma unroll
    for (int ch = 0; ch < 5; ++ch)
      afr[ch] = *(const f16x8*)(hrow(cl) + ch * 32 + q * 8);

    for (int cg = 0; cg < 8; ++cg) {  // chunk idx = cg; contains gates i,f,g,o for cg
      stage_chunk((cg + 1) & 31, sbuf(cg + 1), w, lane, Wg, W1p, W2p);
      const _Float16* buf = sbuf(cg);
      f32x4 gacc[4];
#pragma unroll
      for (int g = 0; g < 4; ++g) gacc[g] = f32x4{0.f, 0.f, 0.f, 0.f};
#pragma unroll
      for (int g = 0; g < 4; ++g) {
        const _Float16* bp = buf + g * 2560 + lane * 8;
#pragma unroll
        for (int ch = 0; ch < 5; ++ch) {
          f16x8 b = *(const f16x8*)(bp + ch * 512);
          gacc[g] = mfma16(afr[ch], b, gacc[g]);
        }
      }
#pragma unroll
      for (int r = 0; r < 4; ++r) {
        const float iv = sigm(gacc[0][r] + bgh[cg][0]);
        const float fv = sigm(gacc[1][r] + bgh[cg][1]);
        const float gv = tanhf_(gacc[2][r] + bgh[cg][2]);
        const float ov = sigm(gacc[3][r] + bgh[cg][3]);
        const float cn = fv * cacc[cg][r] + iv * gv;
        cacc[cg][r] = cn;
        const float hv = ov * tanhf_(cn);
        hc[cg][r] = hv;
        hrow(q * 4 + r)[cg * 16 + cl] = (_Float16)hv;
      }
      __syncthreads();
    }

    // ======== 6 mode heads (A-fragment constant across modes) ========
    f16x8 frag[4];
#pragma unroll
    for (int ch = 0; ch < 4; ++ch)
      frag[ch] = *(const f16x8*)(hrow(cl) + ch * 32 + q * 8);

    for (int m = 0; m < MM; ++m) {
      const int base = 8 + m * 4;
      // GN1 params: vector loads issued early; next barrier drains them free
      const float* pAv = ppA + (m * 16 + cl) * 16;
      const f32x4 g1wA = *(const f32x4*)(pAv);
      const f32x4 g1wB = *(const f32x4*)(pAv + 4);
      const f32x4 g1bA = *(const f32x4*)(pAv + 8);
      const f32x4 g1bB = *(const f32x4*)(pAv + 12);

      f32x4 acc1[8];
      stage_chunk((base + 1) & 31, sbuf(base + 1), w, lane, Wg, W1p, W2p);
      gemm_half(frag, sbuf(base), lane, acc1, 0);
      __syncthreads();
      stage_chunk((base + 2) & 31, sbuf(base + 2), w, lane, Wg, W1p, W2p);
      gemm_half(frag, sbuf(base + 1), lane, acc1, 4);
      // GN1 (DPP rowsum) + relu -> t1; overlaps the staged load
      f32x4 mean, rstd;
      {
        f32x4 s1 = {0.f, 0.f, 0.f, 0.f}, s2 = {0.f, 0.f, 0.f, 0.f};
#pragma unroll
        for (int ct = 0; ct < 8; ++ct) { s1 += acc1[ct]; s2 += acc1[ct] * acc1[ct]; }
        s1 = rowsum16x4(s1); s2 = rowsum16x4(s2);
        mean = s1 * (1.f / 128.f);
#pragma unroll
        for (int r = 0; r < 4; ++r)
          rstd[r] = rsqrtf(s2[r] * (1.f / 128.f) - mean[r] * mean[r] + 1e-5f);
      }
#pragma unroll
      for (int ct = 0; ct < 8; ++ct) {
        const float g1 = (ct < 4) ? g1wA[ct & 3] : g1wB[ct & 3];
        const float b1 = (ct < 4) ? g1bA[ct & 3] : g1bB[ct & 3];
#pragma unroll
        for (int r = 0; r < 4; ++r) {
          float v = (acc1[ct][r] - mean[r]) * rstd[r] * g1 + b1;
          t1row(q * 4 + r)[ct * 16 + cl] = (_Float16)fmaxf(v, 0.f);
        }
      }
      __syncthreads();
      // GN2/out-proj params early (drained by next barrier)
      const float* pBv = ppB + (m * 16 + cl) * 32;
      const f32x4 g2wA = *(const f32x4*)(pBv);
      const f32x4 g2wB = *(const f32x4*)(pBv + 4);
      const f32x4 g2bA = *(const f32x4*)(pBv + 8);
      const f32x4 g2bB = *(const f32x4*)(pBv + 12);
      const f32x4 w0A  = *(const f32x4*)(pBv + 16);
      const f32x4 w0B  = *(const f32x4*)(pBv + 20);
      const f32x4 w1A  = *(const f32x4*)(pBv + 24);
      const f32x4 w1B  = *(const f32x4*)(pBv + 28);
      // gemm2 from t1 (same-wave LDS write->read is in-order; no barrier needed)
      f16x8 at1[4];
#pragma unroll
      for (int ch = 0; ch < 4; ++ch)
        at1[ch] = *(const f16x8*)(t1row(cl) + ch * 32 + q * 8);
      f32x4 acc2[8];
      stage_chunk((base + 3) & 31, sbuf(base + 3), w, lane, Wg, W1p, W2p);
      gemm_half(at1, sbuf(base + 2), lane, acc2, 0);
      __syncthreads();
      stage_chunk((base + 4) & 31, sbuf(base + 4), w, lane, Wg, W1p, W2p);
      gemm_half(at1, sbuf(base + 3), lane, acc2, 4);
      // GN2 (DPP rowsum) + residual (hc regs) + out-proj
      f32x4 mean2, rstd2;
      {
        f32x4 s1 = {0.f, 0.f, 0.f, 0.f}, s2 = {0.f, 0.f, 0.f, 0.f};
#pragma unroll
        for (int ct = 0; ct < 8; ++ct) { s1 += acc2[ct]; s2 += acc2[ct] * acc2[ct]; }
        s1 = rowsum16x4(s1); s2 = rowsum16x4(s2);
        mean2 = s1 * (1.f / 128.f);
#pragma unroll
        for (int r = 0; r < 4; ++r)
          rstd2[r] = rsqrtf(s2[r] * (1.f / 128.f) - mean2[r] * mean2[r] + 1e-5f);
      }
      f32x4 po0 = {0.f, 0.f, 0.f, 0.f}, po1 = {0.f, 0.f, 0.f, 0.f};
#pragma unroll
      for (int ct = 0; ct < 8; ++ct) {
        const float g2 = (ct < 4) ? g2wA[ct & 3] : g2wB[ct & 3];
        const float b2 = (ct < 4) ? g2bA[ct & 3] : g2bB[ct & 3];
        const float w0 = (ct < 4) ? w0A[ct & 3] : w0B[ct & 3];
        const float w1 = (ct < 4) ? w1A[ct & 3] : w1B[ct & 3];
#pragma unroll
        for (int r = 0; r < 4; ++r) {
          float v = (acc2[ct][r] - mean2[r]) * rstd2[r] * g2 + b2 + hc[ct][r];
          v = fmaxf(v, 0.f);
          po0[r] += v * w0;
          po1[r] += v * w1;
        }
      }
      po0 = rowsum16x4(po0);
      po1 = rowsum16x4(po1);
      if (cl < 2) {
#pragma unroll
        for (int r = 0; r < 4; ++r) {
          const int rl_ = q * 4 + r;
          relw[rl_ * 12 + m * 2 + cl] = (cl ? po1[r] : po0[r]) + mbo[m * 2 + cl];
        }
      }
      __syncthreads();
    }

    // ======== step tail: shift-register out buffering + xin (wave-local) ========
    {
      // rotate and insert this step's float2 per (row,mode) pair
      bA0 = bA1; bA1 = bA2; bA2 = bA3; bA3 = bA4; bA4 = bA5;
      bA5.x = relw[rlA]; bA5.y = relw[rlA + 1];
      bB0 = bB1; bB1 = bB2; bB2 = bB3; bB3 = bB4; bB4 = bB5;
      bB5.x = relw[rlB]; bB5.y = relw[rlB + 1];
      if ((t % 6) == 5) {  // flush 48B of one line back-to-back -> L2 merges
        const size_t ta = obA + (size_t)(t - 5);
        *(float2*)(out + (ta + 0) * 2) = bA0;
        *(float2*)(out + (ta + 1) * 2) = bA1;
        *(float2*)(out + (ta + 2) * 2) = bA2;
        *(float2*)(out + (ta + 3) * 2) = bA3;
        *(float2*)(out + (ta + 4) * 2) = bA4;
        *(float2*)(out + (ta + 5) * 2) = bA5;
        if (lane < 32) {
          const size_t tb = obB + (size_t)(t - 5);
          *(float2*)(out + (tb + 0) * 2) = bB0;
          *(float2*)(out + (tb + 1) * 2) = bB1;
          *(float2*)(out + (tb + 2) * 2) = bB2;
          *(float2*)(out + (tb + 3) * 2) = bB3;
          *(float2*)(out + (tb + 4) * 2) = bB4;
          *(float2*)(out + (tb + 5) * 2) = bB5;
        }
      }
    }
    {
      const int rr = lane & 15;
      const f32x4 rl0 = *(const f32x4*)(relw + rr * 12);
      const f32x4 rl1 = *(const f32x4*)(relw + rr * 12 + 4);
      const f32x4 rl2 = *(const f32x4*)(relw + rr * 12 + 8);
      f32x4 wv0, wv1, wv2, bsv;
      bsv = *(const f32x4*)(wsp + 48);
      f16x4 v;
#pragma unroll
      for (int i = 0; i < 4; ++i) {
        wv0 = *(const f32x4*)(wsp + i * 12);
        wv1 = *(const f32x4*)(wsp + i * 12 + 4);
        wv2 = *(const f32x4*)(wsp + i * 12 + 8);
        float acc = bsv[i];
#pragma unroll
        for (int j = 0; j < 4; ++j) acc += rl0[j] * wv0[j];
#pragma unroll
        for (int j = 0; j < 4; ++j) acc += rl1[j] * wv1[j];
#pragma unroll
        for (int j = 0; j < 4; ++j) acc += rl2[j] * wv2[j];
        v[i] = (_Float16)selu_(acc);
      }
      *(f16x4*)(hrow(rr) + 128 + (lane >> 4) * 4) = v;
    }
    // no barrier: h/x/rel are wave-private; staging WAR is covered by the
    // mode-5 sync above (next overwrite of that buffer is 2 chunks away)
  }

  // ======== confidence head on hT (wave-local; weights from global) ========
  {
    f16x8 frag[4];
#pragma unroll
    for (int ch = 0; ch < 4; ++ch)
      frag[ch] = *(const f16x8*)(hrow(cl) + ch * 32 + q * 8);
    f32x4 acc1[8];
#pragma unroll
    for (int ct = 0; ct < 8; ++ct) {
      const _Float16* bp = cW1p + ct * 2048 + lane * 8;
      f32x4 a0 = {0.f, 0.f, 0.f, 0.f};
#pragma unroll
      for (int ch = 0; ch < 4; ++ch) {
        f16x8 b = *(const f16x8*)(bp + ch * 512);
        a0 = mfma16(frag[ch], b, a0);
      }
      acc1[ct] = a0;
    }
    f32x4 mean, rstd;
    {
      f32x4 s1 = {0.f, 0.f, 0.f, 0.f}, s2 = {0.f, 0.f, 0.f, 0.f};
#pragma unroll
      for (int ct = 0; ct < 8; ++ct) { s1 += acc1[ct]; s2 += acc1[ct] * acc1[ct]; }
      s1 = rowsum16x4(s1); s2 = rowsum16x4(s2);
      mean = s1 * (1.f / 128.f);
#pragma unroll
      for (int r = 0; r < 4; ++r)
        rstd[r] = rsqrtf(s2[r] * (1.f / 128.f) - mean[r] * mean[r] + 1e-5f);
    }
#pragma unroll
    for (int ct = 0; ct < 8; ++ct) {
      const float g1 = cg1w[ct * 16 + cl];
      const float b1 = cg1b[ct * 16 + cl];
#pragma unroll
      for (int r = 0; r < 4; ++r) {
        float v = (acc1[ct][r] - mean[r]) * rstd[r] * g1 + b1;
        t1row(q * 4 + r)[ct * 16 + cl] = (_Float16)fmaxf(v, 0.f);
      }
    }
    f16x8 at1[4];
#pragma unroll
    for (int ch = 0; ch < 4; ++ch)
      at1[ch] = *(const f16x8*)(t1row(cl) + ch * 32 + q * 8);
    f32x4 acc2[8];
#pragma unroll
    for (int ct = 0; ct < 8; ++ct) {
      const _Float16* bp = cW2p + ct * 2048 + lane * 8;
      f32x4 a0 = {0.f, 0.f, 0.f, 0.f};
#pragma unroll
      for (int ch = 0; ch < 4; ++ch) {
        f16x8 b = *(const f16x8*)(bp + ch * 512);
        a0 = mfma16(at1[ch], b, a0);
      }
      acc2[ct] = a0;
    }
    f32x4 mean2, rstd2;
    {
      f32x4 s1 = {0.f, 0.f, 0.f, 0.f}, s2 = {0.f, 0.f, 0.f, 0.f};
#pragma unroll
      for (int ct = 0; ct < 8; ++ct) { s1 += acc2[ct]; s2 += acc2[ct] * acc2[ct]; }
      s1 = rowsum16x4(s1); s2 = rowsum16x4(s2);
      mean2 = s1 * (1.f / 128.f);
#pragma unroll
      for (int r = 0; r < 4; ++r)
        rstd2[r] = rsqrtf(s2[r] * (1.f / 128.f) - mean2[r] * mean2[r] + 1e-5f);
    }
    float pl[4][6];
#pragma unroll
    for (int r = 0; r < 4; ++r)
#pragma unroll
      for (int k = 0; k < 6; ++k) pl[r][k] = 0.f;
#pragma unroll
    for (int ct = 0; ct < 8; ++ct) {
      const float g2 = cg2w[ct * 16 + cl];
      const float b2 = cg2b[ct * 16 + cl];
      float wo[6];
#pragma unroll
      for (int k = 0; k < 6; ++k) wo[k] = cWo[(ct * 16 + cl) * 6 + k];
#pragma unroll
      for (int r = 0; r < 4; ++r) {
        float v = (acc2[ct][r] - mean2[r]) * rstd2[r] * g2 + b2 + hc[ct][r];
        v = fmaxf(v, 0.f);
#pragma unroll
        for (int k = 0; k < 6; ++k) pl[r][k] += v * wo[k];
      }
    }
#pragma unroll
    for (int r = 0; r < 4; ++r)
#pragma unroll
      for (int k = 0; k < 6; ++k) pl[r][k] = rowsum16(pl[r][k]);
    if (cl == 0) {
#pragma unroll
      for (int r = 0; r < 4; ++r) {
        float l[6];
#pragma unroll
        for (int k = 0; k < 6; ++k) l[k] = pl[r][k] + cbo[k];
        float mx = l[0];
#pragma unroll
        for (int k = 1; k < 6; ++k) mx = fmaxf(mx, l[k]);
        float s = 0.f;
#pragma unroll
        for (int k = 0; k < 6; ++k) { l[k] = __expf(l[k] - mx); s += l[k]; }
        const float inv = fast_rcp(s);
#pragma unroll
        for (int k = 0; k < 6; ++k)
          out[confbase + (size_t)(rowbase + q * 4 + r) * 6 + k] = l[k] * inv;
      }
    }
  }
}

extern "C" void kernel_launch(void* const* d_in, const int* in_sizes, int n_in,
                              void* d_out, int out_size, void* d_ws, size_t ws_size,
                              hipStream_t stream) {
  (void)in_sizes; (void)n_in; (void)out_size; (void)ws_size;
  const float* last_obs_rel = (const float*)d_in[1];
  const float* h0   = (const float*)d_in[2];
  const float* c0   = (const float*)d_in[3];
  const float* W_se = (const float*)d_in[4];
  const float* b_se = (const float*)d_in[5];
  const float* W_ih = (const float*)d_in[6];
  const float* W_hh = (const float*)d_in[7];
  const float* b_ih = (const float*)d_in[8];
  const float* b_hh = (const float*)d_in[9];
  const float* mW1  = (const float*)d_in[10];
  const float* mg1w = (const float*)d_in[11];
  const float* mg1b = (const float*)d_in[12];
  const float* mW2  = (const float*)d_in[13];
  const float* mg2w = (const float*)d_in[14];
  const float* mg2b = (const float*)d_in[15];
  const float* mWo  = (const float*)d_in[16];
  const float* mbo  = (const float*)d_in[17];
  const float* cW1  = (const float*)d_in[18];
  const float* cg1w = (const float*)d_in[19];
  const float* cg1b = (const float*)d_in[20];
  const float* cW2  = (const float*)d_in[21];
  const float* cg2w = (const float*)d_in[22];
  const float* cg2b = (const float*)d_in[23];
  const float* cWo  = (const float*)d_in[24];
  const float* cbo  = (const float*)d_in[25];

  char* ws = (char*)d_ws;
  _Float16* Wg   = (_Float16*)(ws + 0);       // 512*160 f16   = 163840 B
  _Float16* W1p  = (_Float16*)(ws + 163840);  // 6*128*128 f16 = 196608 B
  _Float16* W2p  = (_Float16*)(ws + 360448);  // 6*128*128 f16 = 196608 B
  _Float16* cW1p = (_Float16*)(ws + 557056);  // 128*128 f16   =  32768 B
  _Float16* cW2p = (_Float16*)(ws + 589824);  // 128*128 f16   =  32768 B
  float*    bg   = (float*)   (ws + 622592);  // 512 f32       =   2048 B
  float*    ppA  = (float*)   (ws + 624640);  // 1536 f32      =   6144 B
  float*    ppB  = (float*)   (ws + 630784);  // 3072 f32      =  12288 B
  float*    ppC  = (float*)   (ws + 643072);  // 224 f32       =    896 B

  prep_weights<<<1237, 256, 0, stream>>>(W_ih, W_hh, b_ih, b_hh, mW1, mW2, cW1, cW2,
                                         mg1w, mg1b, mg2w, mg2b, mWo, W_se, b_se,
                                         Wg, W1p, W2p, cW1p, cW2p, bg, ppA, ppB, ppC);
  mmdec_main<<<B_ROWS / 64, 256, 0, stream>>>(last_obs_rel, h0, c0,
                                              mbo, cg1w, cg1b, cg2w, cg2b, cWo, cbo,
                                              Wg, W1p, W2p, cW1p, cW2p, bg,
                                              ppA, ppB, ppC, (float*)d_out);
}

// Round 13
// 1694.900 us; speedup vs baseline: 1.1617x; 1.0241x over previous
//
#include <hip/hip_runtime.h>
#include <hip/hip_bf16.h>
#include <cstdint>
#include <cstddef>

// MMDecoderDoubleBranch R19 = R14 (verified best 1702us) + isolated T5
// s_setprio(1) around MFMA clusters. Final lever: R15 (counted vmcnt) flat,
// R16 (epi pipelining) I$-regressed, R17 (body fold) regressed, R18 (write
// coalescing) mechanism-confirmed but latency-hidden (flat). Plateau cause:
// LDS pipe ~690us/CU of ds_read_b128 issue (577/wave/step, irreducible
// without 32-row waves = measured-bad R6 occupancy regime) + barrier-coupled
// latency. T5 was never isolated: 2 independent blocks/CU drift -> role
// diversity exists (attn-like, +4-7% there); lockstep-GEMM null doesn't
// apply cleanly. 2-instr edit, zero structure/code-size change otherwise.
// Pre-committed: if flat -> declared plateau.

#define HD 128
#define TT 30
#define MM 6
#define B_ROWS 32768

typedef _Float16 f16x8 __attribute__((ext_vector_type(8)));
typedef _Float16 f16x4 __attribute__((ext_vector_type(4)));
typedef float f32x4 __attribute__((ext_vector_type(4)));

__device__ __forceinline__ float fast_rcp(float x) { return __builtin_amdgcn_rcpf(x); }
__device__ __forceinline__ float sigm(float x) { return fast_rcp(1.f + __expf(-x)); }
__device__ __forceinline__ float tanhf_(float x) { return 1.f - 2.f * fast_rcp(__expf(2.f * x) + 1.f); }
__device__ __forceinline__ float selu_(float x) {
  const float sc = 1.0507009873554805f;
  const float al = 1.6732632423543772f;
  return x > 0.f ? sc * x : sc * al * (__expf(x) - 1.f);
}

// ---- DPP row (16-lane) sum: every lane gets the sum of its 16-lane group ----
template <int CTRL>
__device__ __forceinline__ float dpp_add(float x) {
  union { float f; int i; } a, b;
  a.f = x;
  b.i = __builtin_amdgcn_update_dpp(a.i, a.i, CTRL, 0xF, 0xF, false);
  return x + b.f;
}
__device__ __forceinline__ float rowsum16(float x) {
  x = dpp_add<0x128>(x);  // row_ror:8
  x = dpp_add<0x124>(x);  // row_ror:4
  x = dpp_add<0x122>(x);  // row_ror:2
  x = dpp_add<0x121>(x);  // row_ror:1
  return x;
}
__device__ __forceinline__ f32x4 rowsum16x4(f32x4 v) {
  v[0] = rowsum16(v[0]); v[1] = rowsum16(v[1]);
  v[2] = rowsum16(v[2]); v[3] = rowsum16(v[3]);
  return v;
}

// ---- weight prep: fragment-ordered f16 + packed epilogue params (== R14) ----
__global__ __launch_bounds__(256) void prep_weights(
    const float* __restrict__ W_ih, const float* __restrict__ W_hh,
    const float* __restrict__ b_ih, const float* __restrict__ b_hh,
    const float* __restrict__ mW1, const float* __restrict__ mW2,
    const float* __restrict__ cW1, const float* __restrict__ cW2,
    const float* __restrict__ mg1w, const float* __restrict__ mg1b,
    const float* __restrict__ mg2w, const float* __restrict__ mg2b,
    const float* __restrict__ mWo, const float* __restrict__ W_se,
    const float* __restrict__ b_se,
    _Float16* __restrict__ Wg, _Float16* __restrict__ W1p, _Float16* __restrict__ W2p,
    _Float16* __restrict__ cW1p, _Float16* __restrict__ cW2p, float* __restrict__ bg,
    float* __restrict__ ppA, float* __restrict__ ppB, float* __restrict__ ppC) {
  int n = blockIdx.x * 256 + threadIdx.x;
  if (n < 81920) {
    int t16 = n / 2560, r = n % 2560;
    int ch = r / 512, l = (r >> 3) & 63, j = r & 7;
    int q = l >> 4, cl = l & 15;
    int cg = t16 >> 2, g = t16 & 3;            // cg-major tile order
    int row = g * 128 + cg * 16 + cl;          // gate-major output row
    int k = ch * 32 + q * 8 + j;
    float v = 0.f;
    if (k < 128) v = W_hh[row * 128 + k];
    else if (k < 144) v = W_ih[row * 16 + (k - 128)];
    Wg[n] = (_Float16)v;
    return;
  }
  n -= 81920;
  if (n < 98304) {
    int m = n >> 14, r = n & 16383;
    int ct = r >> 11, ch = (r >> 9) & 3, l = (r >> 3) & 63, j = r & 7;
    int q = l >> 4, cl = l & 15;
    int outcol = ct * 16 + cl, k = ch * 32 + q * 8 + j;
    W1p[n] = (_Float16)mW1[(m * 128 + k) * 128 + outcol];
    return;
  }
  n -= 98304;
  if (n < 98304) {
    int m = n >> 14, r = n & 16383;
    int ct = r >> 11, ch = (r >> 9) & 3, l = (r >> 3) & 63, j = r & 7;
    int q = l >> 4, cl = l & 15;
    int outcol = ct * 16 + cl, k = ch * 32 + q * 8 + j;
    W2p[n] = (_Float16)mW2[(m * 128 + k) * 128 + outcol];
    return;
  }
  n -= 98304;
  if (n < 16384) {
    int ct = n >> 11, ch = (n >> 9) & 3, l = (n >> 3) & 63, j = n & 7;
    int q = l >> 4, cl = l & 15;
    int outcol = ct * 16 + cl, k = ch * 32 + q * 8 + j;
    cW1p[n] = (_Float16)cW1[k * 128 + outcol];
    return;
  }
  n -= 16384;
  if (n < 16384) {
    int ct = n >> 11, ch = (n >> 9) & 3, l = (n >> 3) & 63, j = n & 7;
    int q = l >> 4, cl = l & 15;
    int outcol = ct * 16 + cl, k = ch * 32 + q * 8 + j;
    cW2p[n] = (_Float16)cW2[k * 128 + outcol];
    return;
  }
  n -= 16384;
  if (n < 512) { bg[n] = b_ih[n] + b_hh[n]; return; }
  n -= 512;
  if (n < 1536) {  // ppA
    int m = n >> 8, r = n & 255;
    int cl = r >> 4, k = r & 15;
    float v = (k < 8) ? mg1w[m * 128 + k * 16 + cl] : mg1b[m * 128 + (k - 8) * 16 + cl];
    ppA[n] = v;
    return;
  }
  n -= 1536;
  if (n < 3072) {  // ppB
    int m = n >> 9, r = n & 511;
    int cl = r >> 5, k = r & 31;
    int ct = k & 7, sel = k >> 3;
    float v;
    if (sel == 0)      v = mg2w[m * 128 + ct * 16 + cl];
    else if (sel == 1) v = mg2b[m * 128 + ct * 16 + cl];
    else               v = mWo[((size_t)m * 128 + ct * 16 + cl) * 2 + (sel - 2)];
    ppB[n] = v;
    return;
  }
  n -= 3072;
  if (n < 224) {  // ppC
    int g = n / 56, k = n % 56;
    float v = 0.f;
    if (k < 48)      v = W_se[(g * 4 + k / 12) * 12 + (k % 12)];
    else if (k < 52) v = b_se[g * 4 + (k - 48)];
    ppC[n] = v;
    return;
  }
}

// chunk schedule (32 chunks/step, same weights every step):
//   idx 0..7  : Wg + idx*10240, 20 x 1KB
//   idx 8..31 : j=idx-8, m=j>>2, r=j&3 -> (r<2?W1p:W2p)+m*16384+(r&1)*8192, 16 x 1KB
// 4 waves split the 1KB blocks of a chunk (i = w, w+4, ...).
__device__ __forceinline__ void stage_chunk(int idx, _Float16* dst, int w, int lane,
                                            const _Float16* __restrict__ Wg,
                                            const _Float16* __restrict__ W1p,
                                            const _Float16* __restrict__ W2p) {
  const _Float16* src;
  int nblk;
  if (idx < 8) {
    src = Wg + idx * 10240;
    nblk = 20;
  } else {
    int j = idx - 8, m = j >> 2, r = j & 3;
    src = ((r & 2) ? W2p : W1p) + m * 16384 + (r & 1) * 8192;
    nblk = 16;
  }
  for (int i = w; i < nblk; i += 4) {
    __builtin_amdgcn_global_load_lds(
        (const __attribute__((address_space(1))) void*)(src + i * 512 + lane * 8),
        (__attribute__((address_space(3))) void*)(dst + i * 512 + lane * 8),
        16, 0, 0);
  }
}

__device__ __forceinline__ f32x4 mfma16(f16x8 a, f16x8 b, f32x4 c) {
  return __builtin_amdgcn_mfma_f32_16x16x32_f16(a, b, c, 0, 0, 0);
}

// one half (4 col-tiles) of a 16x128 GEMM slice from a staged LDS buffer
// T5: boost wave priority across the MFMA cluster (2 drifting blocks/CU).
__device__ __forceinline__ void gemm_half(const f16x8 (&a)[4], const _Float16* buf,
                                          int lane, f32x4 (&acc)[8], int base) {
  __builtin_amdgcn_s_setprio(1);
#pragma unroll
  for (int ctl = 0; ctl < 4; ++ctl) {
    const _Float16* bp = buf + ctl * 2048 + lane * 8;
    f32x4 a0 = {0.f, 0.f, 0.f, 0.f};
#pragma unroll
    for (int ch = 0; ch < 4; ++ch) {
      f16x8 b = *(const f16x8*)(bp + ch * 512);
      a0 = mfma16(a[ch], b, a0);
    }
    acc[base + ctl] = a0;
  }
  __builtin_amdgcn_s_setprio(0);
}

// ---- main decoder: 512 blocks x 4 waves; wave owns 16 rows end-to-end ----
__global__ __launch_bounds__(256, 2) void mmdec_main(
    const float* __restrict__ last_obs_rel, const float* __restrict__ h0, const float* __restrict__ c0,
    const float* __restrict__ mbo, const float* __restrict__ cg1w, const float* __restrict__ cg1b,
    const float* __restrict__ cg2w, const float* __restrict__ cg2b,
    const float* __restrict__ cWo, const float* __restrict__ cbo,
    const _Float16* __restrict__ Wg, const _Float16* __restrict__ W1p, const _Float16* __restrict__ W2p,
    const _Float16* __restrict__ cW1p, const _Float16* __restrict__ cW2p, const float* __restrict__ bgp,
    const float* __restrict__ ppA, const float* __restrict__ ppB, const float* __restrict__ ppC,
    float* __restrict__ out) {
  // LDS map (bytes): stage 2x20480 | h 64x320 | t1 64x272 | rel 64x12 f32
  __shared__ __align__(16) unsigned char smem[81920];
  _Float16* stage0 = (_Float16*)smem;                       // [0, 40960)
  unsigned char* h_base = smem + 40960;                     // [40960, 61440)
  unsigned char* t1_base = smem + 61440;                    // [61440, 78848)
  float* rel_all = (float*)(smem + 78848);                  // [78848, 81920)

  const int tid = threadIdx.x;
  const int w = tid >> 6;       // wave id 0..3: owns rows [16w, 16w+16) of block
  const int lane = tid & 63;
  const int q = lane >> 4, cl = lane & 15;
  const int rowbase = blockIdx.x * 64 + w * 16;             // wave's first global row

  auto hrow = [&](int r) -> _Float16* { return (_Float16*)(h_base + (w * 16 + r) * 320); };
  auto t1row = [&](int r) -> _Float16* { return (_Float16*)(t1_base + (w * 16 + r) * 272); };
  float* relw = rel_all + w * 16 * 12;

  auto sbuf = [&](int idx) -> _Float16* { return stage0 + ((idx & 1) ? 10240 : 0); };

  // ---- init: h0 -> LDS f16 (quarter row per lane, float4 loads) ----
  {
    const int rr = lane & 15, seg = lane >> 4;
    const float* src = h0 + (size_t)(rowbase + rr) * HD + seg * 32;
    _Float16* dst = hrow(rr) + seg * 32;
#pragma unroll
    for (int i = 0; i < 32; i += 8) {
      f32x4 a = *(const f32x4*)(src + i);
      f32x4 b = *(const f32x4*)(src + i + 4);
      f16x8 v;
#pragma unroll
      for (int k = 0; k < 4; ++k) { v[k] = (_Float16)a[k]; v[4 + k] = (_Float16)b[k]; }
      *(f16x8*)(dst + i) = v;
    }
    // x = selu(tile(last_obs_rel,6) @ W_se.T + b_se); 4 E-cols per lane
    const float r0 = last_obs_rel[(size_t)(rowbase + rr) * 2 + 0];
    const float r1 = last_obs_rel[(size_t)(rowbase + rr) * 2 + 1];
    const int e0 = seg * 4;
    f16x4 v;
#pragma unroll
    for (int i = 0; i < 4; ++i) {
      float acc = ppC[seg * 56 + 48 + i];
#pragma unroll
      for (int j = 0; j < 12; ++j) acc += ((j & 1) ? r1 : r0) * ppC[seg * 56 + i * 12 + j];
      v[i] = (_Float16)selu_(acc);
    }
    *(f16x4*)(hrow(rr) + 128 + e0) = v;
    if (lane < 16) {  // zero pad cols 144..159
      f16x8 z;
#pragma unroll
      for (int i = 0; i < 8; ++i) z[i] = (_Float16)0.f;
      *(f16x8*)(hrow(lane) + 144) = z;
      *(f16x8*)(hrow(lane) + 152) = z;
    }
  }
  // ---- init: c0 in C-layout regs [cg] ----
  f32x4 cacc[8];
#pragma unroll
  for (int cg = 0; cg < 8; ++cg)
#pragma unroll
    for (int r = 0; r < 4; ++r)
      cacc[cg][r] = c0[(size_t)(rowbase + q * 4 + r) * HD + cg * 16 + cl];
  float bgh[8][4];
#pragma unroll
  for (int cg = 0; cg < 8; ++cg)
#pragma unroll
    for (int g = 0; g < 4; ++g) bgh[cg][g] = bgp[g * 128 + cg * 16 + cl];
  f32x4 hc[8];  // h(t) in C-layout (residual source)

  // ---- batched out-store precompute: 96 (row,mode) pairs per wave ----
  const int pA_ = lane, pB_ = 64 + lane;
  const size_t obA = ((size_t)(rowbase + pA_ / 6) * MM + pA_ % 6) * TT;
  const size_t obB = ((size_t)(rowbase + pB_ / 6) * MM + pB_ % 6) * TT;
  const int rlA = (pA_ / 6) * 12 + (pA_ % 6) * 2;
  const int rlB = (pB_ / 6) * 12 + (pB_ % 6) * 2;

  // step-tail W_se pack pointer (per-lane e0 group)
  const float* wsp = ppC + (lane >> 4) * 56;

  // prime the pipeline: stage chunk 0
  stage_chunk(0, sbuf(0), w, lane, Wg, W1p, W2p);
  __syncthreads();

  const size_t confbase = (size_t)B_ROWS * MM * TT * 2;

  for (int t = 0; t < TT; ++t) {
    // ======== LSTM: [h|x|0](K=160) @ Wg^T; c update; h(t) scatter ========
    f16x8 afr[5];
#pragma unroll
    for (int ch = 0; ch < 5; ++ch)
      afr[ch] = *(const f16x8*)(hrow(cl) + ch * 32 + q * 8);

    for (int cg = 0; cg < 8; ++cg) {  // chunk idx = cg; contains gates i,f,g,o for cg
      stage_chunk((cg + 1) & 31, sbuf(cg + 1), w, lane, Wg, W1p, W2p);
      const _Float16* buf = sbuf(cg);
      f32x4 gacc[4];
#pragma unroll
      for (int g = 0; g < 4; ++g) gacc[g] = f32x4{0.f, 0.f, 0.f, 0.f};
      __builtin_amdgcn_s_setprio(1);
#pragma unroll
      for (int g = 0; g < 4; ++g) {
        const _Float16* bp = buf + g * 2560 + lane * 8;
#pragma unroll
        for (int ch = 0; ch < 5; ++ch) {
          f16x8 b = *(const f16x8*)(bp + ch * 512);
          gacc[g] = mfma16(afr[ch], b, gacc[g]);
        }
      }
      __builtin_amdgcn_s_setprio(0);
#pragma unroll
      for (int r = 0; r < 4; ++r) {
        const float iv = sigm(gacc[0][r] + bgh[cg][0]);
        const float fv = sigm(gacc[1][r] + bgh[cg][1]);
        const float gv = tanhf_(gacc[2][r] + bgh[cg][2]);
        const float ov = sigm(gacc[3][r] + bgh[cg][3]);
        const float cn = fv * cacc[cg][r] + iv * gv;
        cacc[cg][r] = cn;
        const float hv = ov * tanhf_(cn);
        hc[cg][r] = hv;
        hrow(q * 4 + r)[cg * 16 + cl] = (_Float16)hv;
      }
      __syncthreads();
    }

    // ======== 6 mode heads (A-fragment constant across modes) ========
    f16x8 frag[4];
#pragma unroll
    for (int ch = 0; ch < 4; ++ch)
      frag[ch] = *(const f16x8*)(hrow(cl) + ch * 32 + q * 8);

    for (int m = 0; m < MM; ++m) {
      const int base = 8 + m * 4;
      // GN1 params: vector loads issued early; next barrier drains them free
      const float* pAv = ppA + (m * 16 + cl) * 16;
      const f32x4 g1wA = *(const f32x4*)(pAv);
      const f32x4 g1wB = *(const f32x4*)(pAv + 4);
      const f32x4 g1bA = *(const f32x4*)(pAv + 8);
      const f32x4 g1bB = *(const f32x4*)(pAv + 12);

      f32x4 acc1[8];
      stage_chunk((base + 1) & 31, sbuf(base + 1), w, lane, Wg, W1p, W2p);
      gemm_half(frag, sbuf(base), lane, acc1, 0);
      __syncthreads();
      stage_chunk((base + 2) & 31, sbuf(base + 2), w, lane, Wg, W1p, W2p);
      gemm_half(frag, sbuf(base + 1), lane, acc1, 4);
      // GN1 (DPP rowsum) + relu -> t1; overlaps the staged load
      f32x4 mean, rstd;
      {
        f32x4 s1 = {0.f, 0.f, 0.f, 0.f}, s2 = {0.f, 0.f, 0.f, 0.f};
#pragma unroll
        for (int ct = 0; ct < 8; ++ct) { s1 += acc1[ct]; s2 += acc1[ct] * acc1[ct]; }
        s1 = rowsum16x4(s1); s2 = rowsum16x4(s2);
        mean = s1 * (1.f / 128.f);
#pragma unroll
        for (int r = 0; r < 4; ++r)
          rstd[r] = rsqrtf(s2[r] * (1.f / 128.f) - mean[r] * mean[r] + 1e-5f);
      }
#pragma unroll
      for (int ct = 0; ct < 8; ++ct) {
        const float g1 = (ct < 4) ? g1wA[ct & 3] : g1wB[ct & 3];
        const float b1 = (ct < 4) ? g1bA[ct & 3] : g1bB[ct & 3];
#pragma unroll
        for (int r = 0; r < 4; ++r) {
          float v = (acc1[ct][r] - mean[r]) * rstd[r] * g1 + b1;
          t1row(q * 4 + r)[ct * 16 + cl] = (_Float16)fmaxf(v, 0.f);
        }
      }
      __syncthreads();
      // GN2/out-proj params early (drained by next barrier)
      const float* pBv = ppB + (m * 16 + cl) * 32;
      const f32x4 g2wA = *(const f32x4*)(pBv);
      const f32x4 g2wB = *(const f32x4*)(pBv + 4);
      const f32x4 g2bA = *(const f32x4*)(pBv + 8);
      const f32x4 g2bB = *(const f32x4*)(pBv + 12);
      const f32x4 w0A  = *(const f32x4*)(pBv + 16);
      const f32x4 w0B  = *(const f32x4*)(pBv + 20);
      const f32x4 w1A  = *(const f32x4*)(pBv + 24);
      const f32x4 w1B  = *(const f32x4*)(pBv + 28);
      // gemm2 from t1 (same-wave LDS write->read is in-order; no barrier needed)
      f16x8 at1[4];
#pragma unroll
      for (int ch = 0; ch < 4; ++ch)
        at1[ch] = *(const f16x8*)(t1row(cl) + ch * 32 + q * 8);
      f32x4 acc2[8];
      stage_chunk((base + 3) & 31, sbuf(base + 3), w, lane, Wg, W1p, W2p);
      gemm_half(at1, sbuf(base + 2), lane, acc2, 0);
      __syncthreads();
      stage_chunk((base + 4) & 31, sbuf(base + 4), w, lane, Wg, W1p, W2p);
      gemm_half(at1, sbuf(base + 3), lane, acc2, 4);
      // GN2 (DPP rowsum) + residual (hc regs) + out-proj
      f32x4 mean2, rstd2;
      {
        f32x4 s1 = {0.f, 0.f, 0.f, 0.f}, s2 = {0.f, 0.f, 0.f, 0.f};
#pragma unroll
        for (int ct = 0; ct < 8; ++ct) { s1 += acc2[ct]; s2 += acc2[ct] * acc2[ct]; }
        s1 = rowsum16x4(s1); s2 = rowsum16x4(s2);
        mean2 = s1 * (1.f / 128.f);
#pragma unroll
        for (int r = 0; r < 4; ++r)
          rstd2[r] = rsqrtf(s2[r] * (1.f / 128.f) - mean2[r] * mean2[r] + 1e-5f);
      }
      f32x4 po0 = {0.f, 0.f, 0.f, 0.f}, po1 = {0.f, 0.f, 0.f, 0.f};
#pragma unroll
      for (int ct = 0; ct < 8; ++ct) {
        const float g2 = (ct < 4) ? g2wA[ct & 3] : g2wB[ct & 3];
        const float b2 = (ct < 4) ? g2bA[ct & 3] : g2bB[ct & 3];
        const float w0 = (ct < 4) ? w0A[ct & 3] : w0B[ct & 3];
        const float w1 = (ct < 4) ? w1A[ct & 3] : w1B[ct & 3];
#pragma unroll
        for (int r = 0; r < 4; ++r) {
          float v = (acc2[ct][r] - mean2[r]) * rstd2[r] * g2 + b2 + hc[ct][r];
          v = fmaxf(v, 0.f);
          po0[r] += v * w0;
          po1[r] += v * w1;
        }
      }
      po0 = rowsum16x4(po0);
      po1 = rowsum16x4(po1);
      if (cl < 2) {
#pragma unroll
        for (int r = 0; r < 4; ++r) {
          const int rl_ = q * 4 + r;
          relw[rl_ * 12 + m * 2 + cl] = (cl ? po1[r] : po0[r]) + mbo[m * 2 + cl];
        }
      }
      __syncthreads();
    }

    // ======== step tail: batched out stores + xin (all wave-local) ========
    {
      float2 vA;
      vA.x = relw[rlA]; vA.y = relw[rlA + 1];
      *(float2*)(out + (obA + t) * 2) = vA;
      if (lane < 32) {
        float2 vB;
        vB.x = relw[rlB]; vB.y = relw[rlB + 1];
        *(float2*)(out + (obB + t) * 2) = vB;
      }
    }
    {
      const int rr = lane & 15;
      const f32x4 rl0 = *(const f32x4*)(relw + rr * 12);
      const f32x4 rl1 = *(const f32x4*)(relw + rr * 12 + 4);
      const f32x4 rl2 = *(const f32x4*)(relw + rr * 12 + 8);
      f32x4 wv0, wv1, wv2, bsv;
      bsv = *(const f32x4*)(wsp + 48);
      f16x4 v;
#pragma unroll
      for (int i = 0; i < 4; ++i) {
        wv0 = *(const f32x4*)(wsp + i * 12);
        wv1 = *(const f32x4*)(wsp + i * 12 + 4);
        wv2 = *(const f32x4*)(wsp + i * 12 + 8);
        float acc = bsv[i];
#pragma unroll
        for (int j = 0; j < 4; ++j) acc += rl0[j] * wv0[j];
#pragma unroll
        for (int j = 0; j < 4; ++j) acc += rl1[j] * wv1[j];
#pragma unroll
        for (int j = 0; j < 4; ++j) acc += rl2[j] * wv2[j];
        v[i] = (_Float16)selu_(acc);
      }
      *(f16x4*)(hrow(rr) + 128 + (lane >> 4) * 4) = v;
    }
    // no barrier: h/x/rel are wave-private; staging WAR is covered by the
    // mode-5 sync above (next overwrite of that buffer is 2 chunks away)
  }

  // ======== confidence head on hT (wave-local; weights from global) ========
  {
    f16x8 frag[4];
#pragma unroll
    for (int ch = 0; ch < 4; ++ch)
      frag[ch] = *(const f16x8*)(hrow(cl) + ch * 32 + q * 8);
    f32x4 acc1[8];
#pragma unroll
    for (int ct = 0; ct < 8; ++ct) {
      const _Float16* bp = cW1p + ct * 2048 + lane * 8;
      f32x4 a0 = {0.f, 0.f, 0.f, 0.f};
#pragma unroll
      for (int ch = 0; ch < 4; ++ch) {
        f16x8 b = *(const f16x8*)(bp + ch * 512);
        a0 = mfma16(frag[ch], b, a0);
      }
      acc1[ct] = a0;
    }
    f32x4 mean, rstd;
    {
      f32x4 s1 = {0.f, 0.f, 0.f, 0.f}, s2 = {0.f, 0.f, 0.f, 0.f};
#pragma unroll
      for (int ct = 0; ct < 8; ++ct) { s1 += acc1[ct]; s2 += acc1[ct] * acc1[ct]; }
      s1 = rowsum16x4(s1); s2 = rowsum16x4(s2);
      mean = s1 * (1.f / 128.f);
#pragma unroll
      for (int r = 0; r < 4; ++r)
        rstd[r] = rsqrtf(s2[r] * (1.f / 128.f) - mean[r] * mean[r] + 1e-5f);
    }
#pragma unroll
    for (int ct = 0; ct < 8; ++ct) {
      const float g1 = cg1w[ct * 16 + cl];
      const float b1 = cg1b[ct * 16 + cl];
#pragma unroll
      for (int r = 0; r < 4; ++r) {
        float v = (acc1[ct][r] - mean[r]) * rstd[r] * g1 + b1;
        t1row(q * 4 + r)[ct * 16 + cl] = (_Float16)fmaxf(v, 0.f);
      }
    }
    f16x8 at1[4];
#pragma unroll
    for (int ch = 0; ch < 4; ++ch)
      at1[ch] = *(const f16x8*)(t1row(cl) + ch * 32 + q * 8);
    f32x4 acc2[8];
#pragma unroll
    for (int ct = 0; ct < 8; ++ct) {
      const _Float16* bp = cW2p + ct * 2048 + lane * 8;
      f32x4 a0 = {0.f, 0.f, 0.f, 0.f};
#pragma unroll
      for (int ch = 0; ch < 4; ++ch) {
        f16x8 b = *(const f16x8*)(bp + ch * 512);
        a0 = mfma16(at1[ch], b, a0);
      }
      acc2[ct] = a0;
    }
    f32x4 mean2, rstd2;
    {
      f32x4 s1 = {0.f, 0.f, 0.f, 0.f}, s2 = {0.f, 0.f, 0.f, 0.f};
#pragma unroll
      for (int ct = 0; ct < 8; ++ct) { s1 += acc2[ct]; s2 += acc2[ct] * acc2[ct]; }
      s1 = rowsum16x4(s1); s2 = rowsum16x4(s2);
      mean2 = s1 * (1.f / 128.f);
#pragma unroll
      for (int r = 0; r < 4; ++r)
        rstd2[r] = rsqrtf(s2[r] * (1.f / 128.f) - mean2[r] * mean2[r] + 1e-5f);
    }
    float pl[4][6];
#pragma unroll
    for (int r = 0; r < 4; ++r)
#pragma unroll
      for (int k = 0; k < 6; ++k) pl[r][k] = 0.f;
#pragma unroll
    for (int ct = 0; ct < 8; ++ct) {
      const float g2 = cg2w[ct * 16 + cl];
      const float b2 = cg2b[ct * 16 + cl];
      float wo[6];
#pragma unroll
      for (int k = 0; k < 6; ++k) wo[k] = cWo[(ct * 16 + cl) * 6 + k];
#pragma unroll
      for (int r = 0; r < 4; ++r) {
        float v = (acc2[ct][r] - mean2[r]) * rstd2[r] * g2 + b2 + hc[ct][r];
        v = fmaxf(v, 0.f);
#pragma unroll
        for (int k = 0; k < 6; ++k) pl[r][k] += v * wo[k];
      }
    }
#pragma unroll
    for (int r = 0; r < 4; ++r)
#pragma unroll
      for (int k = 0; k < 6; ++k) pl[r][k] = rowsum16(pl[r][k]);
    if (cl == 0) {
#pragma unroll
      for (int r = 0; r < 4; ++r) {
        float l[6];
#pragma unroll
        for (int k = 0; k < 6; ++k) l[k] = pl[r][k] + cbo[k];
        float mx = l[0];
#pragma unroll
        for (int k = 1; k < 6; ++k) mx = fmaxf(mx, l[k]);
        float s = 0.f;
#pragma unroll
        for (int k = 0; k < 6; ++k) { l[k] = __expf(l[k] - mx); s += l[k]; }
        const float inv = fast_rcp(s);
#pragma unroll
        for (int k = 0; k < 6; ++k)
          out[confbase + (size_t)(rowbase + q * 4 + r) * 6 + k] = l[k] * inv;
      }
    }
  }
}

extern "C" void kernel_launch(void* const* d_in, const int* in_sizes, int n_in,
                              void* d_out, int out_size, void* d_ws, size_t ws_size,
                              hipStream_t stream) {
  (void)in_sizes; (void)n_in; (void)out_size; (void)ws_size;
  const float* last_obs_rel = (const float*)d_in[1];
  const float* h0   = (const float*)d_in[2];
  const float* c0   = (const float*)d_in[3];
  const float* W_se = (const float*)d_in[4];
  const float* b_se = (const float*)d_in[5];
  const float* W_ih = (const float*)d_in[6];
  const float* W_hh = (const float*)d_in[7];
  const float* b_ih = (const float*)d_in[8];
  const float* b_hh = (const float*)d_in[9];
  const float* mW1  = (const float*)d_in[10];
  const float* mg1w = (const float*)d_in[11];
  const float* mg1b = (const float*)d_in[12];
  const float* mW2  = (const float*)d_in[13];
  const float* mg2w = (const float*)d_in[14];
  const float* mg2b = (const float*)d_in[15];
  const float* mWo  = (const float*)d_in[16];
  const float* mbo  = (const float*)d_in[17];
  const float* cW1  = (const float*)d_in[18];
  const float* cg1w = (const float*)d_in[19];
  const float* cg1b = (const float*)d_in[20];
  const float* cW2  = (const float*)d_in[21];
  const float* cg2w = (const float*)d_in[22];
  const float* cg2b = (const float*)d_in[23];
  const float* cWo  = (const float*)d_in[24];
  const float* cbo  = (const float*)d_in[25];

  char* ws = (char*)d_ws;
  _Float16* Wg   = (_Float16*)(ws + 0);       // 512*160 f16   = 163840 B
  _Float16* W1p  = (_Float16*)(ws + 163840);  // 6*128*128 f16 = 196608 B
  _Float16* W2p  = (_Float16*)(ws + 360448);  // 6*128*128 f16 = 196608 B
  _Float16* cW1p = (_Float16*)(ws + 557056);  // 128*128 f16   =  32768 B
  _Float16* cW2p = (_Float16*)(ws + 589824);  // 128*128 f16   =  32768 B
  float*    bg   = (float*)   (ws + 622592);  // 512 f32       =   2048 B
  float*    ppA  = (float*)   (ws + 624640);  // 1536 f32      =   6144 B
  float*    ppB  = (float*)   (ws + 630784);  // 3072 f32      =  12288 B
  float*    ppC  = (float*)   (ws + 643072);  // 224 f32       =    896 B

  prep_weights<<<1237, 256, 0, stream>>>(W_ih, W_hh, b_ih, b_hh, mW1, mW2, cW1, cW2,
                                         mg1w, mg1b, mg2w, mg2b, mWo, W_se, b_se,
                                         Wg, W1p, W2p, cW1p, cW2p, bg, ppA, ppB, ppC);
  mmdec_main<<<B_ROWS / 64, 256, 0, stream>>>(last_obs_rel, h0, c0,
                                              mbo, cg1w, cg1b, cg2w, cg2b, cWo, cbo,
                                              Wg, W1p, W2p, cW1p, cW2p, bg,
                                              ppA, ppB, ppC, (float*)d_out);
}